// Round 8
// baseline (734.642 us; speedup 1.0000x reference)
//
#include <hip/hip_runtime.h>

// NavAssignNet on MI355X — round 8: persistent mega-kernel for the layer loop.
//   - k_layers: 256 WGs x 256 thr, software grid barrier (atomic + threadfence),
//     24 barriers replace 12 dispatches. Updates re-spread over all 256 CUs:
//     U1 (GEMM-X, x stays in registers across the barrier) -> U2 (LN) -> U3 (GEMM2).
//   - scores fused as final phase. Dispatches 17 -> 5.

typedef short bf16x8 __attribute__((ext_vector_type(8)));
typedef float f32x4 __attribute__((ext_vector_type(4)));

#define DEV static __device__ __forceinline__

DEV unsigned short f2bf(float x) {
    unsigned u = __float_as_uint(x);
    return (unsigned short)((u + 0x7fffu + ((u >> 16) & 1u)) >> 16);
}
DEV void split2(float v, unsigned short& hi, unsigned short& lo) {
    unsigned short h = f2bf(v);
    float fh = __uint_as_float(((unsigned)h) << 16);
    hi = h;
    lo = f2bf(v - fh);
}

// ---- 1. prep+weights (unchanged from round 7) ----
__global__ __launch_bounds__(256) void k_prep_w(const float* __restrict__ edge,
                                                unsigned short* __restrict__ edge_bf,
                                                float* __restrict__ traw,
                                                const float* __restrict__ Wp,
                                                const float* __restrict__ bp,
                                                const float* __restrict__ W_r2t,
                                                const float* __restrict__ b_r2t,
                                                const float* __restrict__ W_t2r,
                                                const float* __restrict__ b_t2r,
                                                const float* __restrict__ W_pt,
                                                const float* __restrict__ W_pr,
                                                const float* __restrict__ Ws1,
                                                unsigned short* __restrict__ WcT,
                                                float* __restrict__ bc,
                                                unsigned short* __restrict__ WTbig,
                                                unsigned short* __restrict__ WT2) {
    if (blockIdx.x < 512) {
        int wg = blockIdx.x;
        int b = wg >> 6, j = wg & 63;
        int t = threadIdx.x;
        int d = t & 127, ih = t >> 7;
        float s = 0.f;
        long base = ((long)(b * 64 + ih * 32) * 64 + j) * 128 + d;
#pragma unroll 8
        for (int ii = 0; ii < 32; ++ii) {
            long idx = base + (long)ii * 8192;
            float v = edge[idx];
            s += v;
            edge_bf[idx] = f2bf(v);
        }
        __shared__ float part[128];
        if (ih == 1) part[d] = s;
        __syncthreads();
        if (ih == 0) traw[(b * 64 + j) * 128 + d] = (s + part[d]) * (1.f / 64.f);
        return;
    }
    int blk0 = blockIdx.x - 512;
    int h = threadIdx.x;
    if (blk0 < 774) {
        int blk = blk0;
        if (blk < 768) {
            int p = blk >> 7, d = blk & 127, l = p >> 1;
            const float* Wb = ((p & 1) ? W_t2r : W_r2t) + l * 512 * 256 + 256 * 256;
            float acc = 0.f;
            for (int k = 0; k < 256; ++k) acc += Wp[d * 256 + k] * Wb[k * 256 + h];
            WcT[p * 32768 + h * 128 + d] = f2bf(acc);
        } else {
            int p = blk - 768, l = p >> 1;
            const float* Wb = ((p & 1) ? W_t2r : W_r2t) + l * 512 * 256 + 256 * 256;
            const float* bm = ((p & 1) ? b_t2r : b_r2t) + l * 256;
            float acc = bm[h];
            for (int k = 0; k < 256; ++k) acc += bp[k] * Wb[k * 256 + h];
            bc[p * 256 + h] = acc;
        }
        return;
    }
    int blk = blk0 - 774, t = threadIdx.x;
    if (blk < 1536) {
        int mat = blk >> 8, hh = blk & 255, l = mat >> 1;
        const float* W = ((mat & 1) ? W_pr : W_pt) + l * 512 * 256;
        unsigned short* dh = WTbig + mat * 262144 + hh * 512;
        unsigned short* dl = dh + 131072;
        for (int k = t; k < 512; k += 256) {
            unsigned short hi, lo;
            split2(W[k * 256 + hh], hi, lo);
            dh[k] = hi; dl[k] = lo;
        }
    } else {
        int m2 = blk - 1536, mat = m2 >> 8, hh = m2 & 255;
        const float* W;
        if (mat == 6) W = Ws1 + 256 * 256;
        else if (mat == 5) W = Ws1;
        else if (mat & 1) W = W_r2t + ((mat >> 1) + 1) * 512 * 256;
        else W = W_t2r + (mat >> 1) * 512 * 256;
        unsigned short* dh = WT2 + mat * 131072 + hh * 256;
        unsigned short* dl = dh + 65536;
        unsigned short hi, lo;
        split2(W[t * 256 + hh], hi, lo);
        dh[t] = hi; dl[t] = lo;
    }
}

// ---- 2. proj (unchanged) ----
__global__ __launch_bounds__(256) void k_proj(const float* __restrict__ robot_raw,
                                              const float* __restrict__ traw,
                                              const float* __restrict__ Wp,
                                              const float* __restrict__ bp,
                                              const float* __restrict__ Wa0,
                                              float* __restrict__ robot_h,
                                              float* __restrict__ target_h,
                                              float* __restrict__ rWa) {
    int h = threadIdx.x;
    int r0 = blockIdx.x * 2;
    int robot = (r0 < 512);
    const float* in;
    float* out;
    if (robot) { in = robot_raw + r0 * 128; out = robot_h + r0 * 256; }
    else       { in = traw + (r0 - 512) * 128; out = target_h + (r0 - 512) * 256; }
    float a0 = 0, a1 = 0;
    for (int k = 0; k < 128; ++k) {
        float w = Wp[k * 256 + h];
        a0 += in[k] * w; a1 += in[128 + k] * w;
    }
    float b = bp[h];
    a0 += b; a1 += b;
    out[h] = a0; out[256 + h] = a1;

    __shared__ float yl[2][257];
    if (robot) { yl[0][h] = a0; yl[1][h] = a1; }
    __syncthreads();
    if (robot) {
        float c0 = 0, c1 = 0;
        for (int k = 0; k < 256; ++k) {
            float w = Wa0[k * 256 + h];
            c0 += yl[0][k] * w; c1 += yl[1][k] * w;
        }
        rWa[r0 * 256 + h] = c0; rWa[(r0 + 1) * 256 + h] = c1;
    }
}

// ---- 3. persistent layer loop ----
__global__ __launch_bounds__(256) void k_layers(
        const unsigned short* __restrict__ edge_bf,
        const unsigned short* __restrict__ WcT_all, const float* __restrict__ bc_all,
        float* __restrict__ rWa, float* __restrict__ tWa, float* __restrict__ agg,
        float* __restrict__ robot_h, float* __restrict__ target_h,
        const unsigned short* __restrict__ WTbig, const unsigned short* __restrict__ WT2,
        unsigned short* __restrict__ yhi, unsigned short* __restrict__ ylo,
        float* __restrict__ parts, unsigned* __restrict__ cnt,
        const float* __restrict__ b_pt, const float* __restrict__ b_pr,
        const float* __restrict__ g_t, const float* __restrict__ g_r,
        const float* __restrict__ be_t, const float* __restrict__ be_r,
        const float* __restrict__ bs1,
        float* __restrict__ rS, float* __restrict__ tST,
        const float* __restrict__ Ws2, const float* __restrict__ bs2,
        float* __restrict__ scores) {
    const int wg = blockIdx.x;          // 256 WGs
    const int tid = threadIdx.x;
    const int w = tid >> 6, lane = tid & 63;
    const int c16 = lane & 15, kg = lane >> 4;

    __shared__ unsigned short Ahi[16 * 512];
    __shared__ unsigned short Alo[16 * 512];
    __shared__ float redx[4][64][4];
    __shared__ float ssum[256];

    int bargen = 0;

    for (int l = 0; l < 3; ++l) {
        for (int half = 0; half < 2; ++half) {
            const int p = 2 * l + half;
            const unsigned short* WcT = WcT_all + p * 32768;
            const float* bcv = bc_all + p * 256;
            const float* rowbias = half ? tWa : rWa;
            float* state = half ? robot_h : target_h;
            const unsigned short* WTm = WTbig + p * 262144;
            const float* bvec = half ? (b_pr + l * 256) : (b_pt + l * 256);
            const float* gv   = half ? (g_r + l * 256)  : (g_t + l * 256);
            const float* bev  = half ? (be_r + l * 256) : (be_t + l * 256);
            int m2 = half ? ((l < 2) ? (2 * l + 1) : 5) : (2 * l);
            const unsigned short* WT2a = WT2 + m2 * 131072;
            float* o2a = half ? ((l < 2) ? rWa : rS) : tWa;
            const int haveB = (!half && l == 2);

            // ===== bigpass phase: 2 tiles per WG =====
            for (int rep = 0; rep < 2; ++rep) {
                int tile = wg * 2 + rep;
                int b = tile >> 6, jj = tile & 63;
                int rstride = (half == 0) ? 8192 : 128;
                const unsigned short* Ap = edge_bf + b * 524288
                    + ((half == 0) ? jj * 128 : jj * 8192) + c16 * rstride + 8 * kg;
                const unsigned short* Bp = WcT + (64 * w + c16) * 128 + 8 * kg;

                bf16x8 av[4][4], bv[4][4];
#pragma unroll
                for (int kk = 0; kk < 4; ++kk) {
#pragma unroll
                    for (int mi = 0; mi < 4; ++mi)
                        av[mi][kk] = *(const bf16x8*)(Ap + mi * 16 * rstride + kk * 32);
#pragma unroll
                    for (int ni = 0; ni < 4; ++ni)
                        bv[ni][kk] = *(const bf16x8*)(Bp + ni * 2048 + kk * 32);
                }
                f32x4 acc[4][4];
#pragma unroll
                for (int mi = 0; mi < 4; ++mi)
#pragma unroll
                    for (int ni = 0; ni < 4; ++ni) acc[mi][ni] = f32x4{0.f, 0.f, 0.f, 0.f};
#pragma unroll
                for (int kk = 0; kk < 4; ++kk)
#pragma unroll
                    for (int mi = 0; mi < 4; ++mi)
#pragma unroll
                        for (int ni = 0; ni < 4; ++ni)
                            acc[mi][ni] = __builtin_amdgcn_mfma_f32_16x16x32_bf16(av[mi][kk], bv[ni][kk], acc[mi][ni], 0, 0, 0);

                const float* rb = rowbias + (b * 64) * 256;
                float colsum[4] = {0.f, 0.f, 0.f, 0.f};
#pragma unroll
                for (int ni = 0; ni < 4; ++ni) {
                    int col = 64 * w + 16 * ni + c16;
                    float bch = bcv[col];
#pragma unroll
                    for (int mi = 0; mi < 4; ++mi) {
                        int rbase = 16 * mi + 4 * kg;
#pragma unroll
                        for (int r = 0; r < 4; ++r) {
                            float v = acc[mi][ni][r] + rb[(rbase + r) * 256 + col] + bch;
                            colsum[ni] += fmaxf(v, 0.f);
                        }
                    }
                }
#pragma unroll
                for (int ni = 0; ni < 4; ++ni) {
                    colsum[ni] += __shfl_xor(colsum[ni], 16);
                    colsum[ni] += __shfl_xor(colsum[ni], 32);
                }
                if (kg == 0) {
                    float* o = agg + (b * 64 + jj) * 256 + 64 * w + c16;
#pragma unroll
                    for (int ni = 0; ni < 4; ++ni) o[16 * ni] = colsum[ni] * (1.f / 64.f);
                }
            }

            // barrier
            { ++bargen; unsigned tgt = 256u * bargen;
              __syncthreads();
              if (tid == 0) { __threadfence(); atomicAdd(cnt, 1u);
                  for (long it = 0; it < (1L << 24); ++it) { if (atomicAdd(cnt, 0u) >= tgt) break; __builtin_amdgcn_s_sleep(2); }
                  __threadfence(); }
              __syncthreads(); }

            // ===== U1: x = [state|agg]@W + state + b  (32 rt x 8 ct), x kept in regs =====
            const int rt = wg >> 3, ct = wg & 7;
            const int r0u = rt * 16;
            float xv[4];
            int colU = 0;
            {
                // stage A rows r0u..+15 (state K0..255 | agg K256..511) as swizzled hi/lo
                int row = tid & 15, kq = tid >> 4;    // kq 0..15, 32 K-elems each
                const float* src = (kq < 8) ? (state + (r0u + row) * 256 + kq * 32)
                                            : (agg + (r0u + row) * 256 + (kq - 8) * 32);
#pragma unroll
                for (int blk = 0; blk < 4; ++blk) {
                    float4 a = *(const float4*)(src + blk * 8);
                    float4 b2 = *(const float4*)(src + blk * 8 + 4);
                    unsigned short h[8], lo[8];
                    split2(a.x, h[0], lo[0]); split2(a.y, h[1], lo[1]);
                    split2(a.z, h[2], lo[2]); split2(a.w, h[3], lo[3]);
                    split2(b2.x, h[4], lo[4]); split2(b2.y, h[5], lo[5]);
                    split2(b2.z, h[6], lo[6]); split2(b2.w, h[7], lo[7]);
                    int byte = row * 1024 + (kq * 32 + blk * 8) * 2;
                    byte ^= (row & 7) << 4;
                    ushort4* ph = (ushort4*)((char*)Ahi + byte);
                    ph[0] = make_ushort4(h[0], h[1], h[2], h[3]);
                    ph[1] = make_ushort4(h[4], h[5], h[6], h[7]);
                    ushort4* pl = (ushort4*)((char*)Alo + byte);
                    pl[0] = make_ushort4(lo[0], lo[1], lo[2], lo[3]);
                    pl[1] = make_ushort4(lo[4], lo[5], lo[6], lo[7]);
                }
                __syncthreads();

                int coltile = w & 1, khalf = w >> 1;
                colU = ct * 32 + coltile * 16 + c16;
                f32x4 acc = f32x4{0.f, 0.f, 0.f, 0.f};
                const unsigned short* Bh0 = WTm + colU * 512 + khalf * 256 + kg * 8;
#pragma unroll 2
                for (int ks = 0; ks < 8; ++ks) {
                    int ab = c16 * 1024 + (khalf * 8 + ks) * 64 + kg * 16;
                    ab ^= (c16 & 7) << 4;
                    bf16x8 ah = *(const bf16x8*)((const char*)Ahi + ab);
                    bf16x8 al = *(const bf16x8*)((const char*)Alo + ab);
                    const unsigned short* pb = Bh0 + ks * 32;
                    bf16x8 bh = *(const bf16x8*)pb;
                    bf16x8 bl = *(const bf16x8*)(pb + 131072);
                    acc = __builtin_amdgcn_mfma_f32_16x16x32_bf16(ah, bh, acc, 0, 0, 0);
                    acc = __builtin_amdgcn_mfma_f32_16x16x32_bf16(al, bh, acc, 0, 0, 0);
                    acc = __builtin_amdgcn_mfma_f32_16x16x32_bf16(ah, bl, acc, 0, 0, 0);
                }
                redx[w][lane][0] = acc[0]; redx[w][lane][1] = acc[1];
                redx[w][lane][2] = acc[2]; redx[w][lane][3] = acc[3];
                __syncthreads();
                if (w < 2) {
                    float bvc = bvec[colU];
#pragma unroll
                    for (int r = 0; r < 4; ++r) {
                        int row2 = kg * 4 + r;
                        xv[r] = acc[r] + redx[w + 2][lane][r]
                              + state[(r0u + row2) * 256 + colU] + bvc;
                    }
                    // LN partials over this wave's 16 cols
                    float s[4], q[4];
#pragma unroll
                    for (int r = 0; r < 4; ++r) {
                        s[r] = xv[r]; q[r] = xv[r] * xv[r];
#pragma unroll
                        for (int m = 1; m < 16; m <<= 1) {
                            s[r] += __shfl_xor(s[r], m);
                            q[r] += __shfl_xor(q[r], m);
                        }
                    }
                    if (c16 == 0) {
                        int pct = ct * 2 + w;
#pragma unroll
                        for (int r = 0; r < 4; ++r) {
                            int grow = r0u + kg * 4 + r;
                            parts[pct * 1024 + grow * 2 + 0] = s[r];
                            parts[pct * 1024 + grow * 2 + 1] = q[r];
                        }
                    }
                }
            }

            // barrier
            { ++bargen; unsigned tgt = 256u * bargen;
              __syncthreads();
              if (tid == 0) { __threadfence(); atomicAdd(cnt, 1u);
                  for (long it = 0; it < (1L << 24); ++it) { if (atomicAdd(cnt, 0u) >= tgt) break; __builtin_amdgcn_s_sleep(2); }
                  __threadfence(); }
              __syncthreads(); }

            // ===== U2: LN(x) -> state, ybf (x from regs) =====
            if (w < 2) {
                float gg = gv[colU], bb = bev[colU];
#pragma unroll
                for (int r = 0; r < 4; ++r) {
                    int grow = r0u + kg * 4 + r;
                    float S = 0.f, Q = 0.f;
#pragma unroll
                    for (int pp = 0; pp < 16; ++pp) {
                        S += parts[pp * 1024 + grow * 2 + 0];
                        Q += parts[pp * 1024 + grow * 2 + 1];
                    }
                    float m = S * (1.f / 256.f);
                    float v = Q * (1.f / 256.f) - m * m;
                    float y = (xv[r] - m) * rsqrtf(v + 1e-5f) * gg + bb;
                    state[grow * 256 + colU] = y;
                    unsigned short yh, yl2;
                    split2(y, yh, yl2);
                    yhi[grow * 256 + colU] = yh;
                    ylo[grow * 256 + colU] = yl2;
                }
            }

            // barrier
            { ++bargen; unsigned tgt = 256u * bargen;
              __syncthreads();
              if (tid == 0) { __threadfence(); atomicAdd(cnt, 1u);
                  for (long it = 0; it < (1L << 24); ++it) { if (atomicAdd(cnt, 0u) >= tgt) break; __builtin_amdgcn_s_sleep(2); }
                  __threadfence(); }
              __syncthreads(); }

            // ===== U3: out2a = y@W2a (wg<128); out2b = y@W2b + b (wg>=128, l==2 target) =====
            {
                int active = (wg < 128) || haveB;
                if (active) {
                    int wg2 = wg & 127;
                    int rt3 = wg2 >> 2, ct4 = wg2 & 3;
                    int col = ct4 * 64 + w * 16 + c16;
                    const unsigned short* WB = (wg < 128) ? WT2a : (WT2 + 6 * 131072);
                    f32x4 acc = f32x4{0.f, 0.f, 0.f, 0.f};
                    const unsigned short* Ay = yhi + (rt3 * 16 + c16) * 256 + kg * 8;
                    const unsigned short* Ay2 = ylo + (rt3 * 16 + c16) * 256 + kg * 8;
                    const unsigned short* Bh0 = WB + col * 256 + kg * 8;
#pragma unroll 2
                    for (int ks = 0; ks < 8; ++ks) {
                        bf16x8 ah = *(const bf16x8*)(Ay + ks * 32);
                        bf16x8 al = *(const bf16x8*)(Ay2 + ks * 32);
                        const unsigned short* pb = Bh0 + ks * 32;
                        bf16x8 bh = *(const bf16x8*)pb;
                        bf16x8 bl = *(const bf16x8*)(pb + 65536);
                        acc = __builtin_amdgcn_mfma_f32_16x16x32_bf16(ah, bh, acc, 0, 0, 0);
                        acc = __builtin_amdgcn_mfma_f32_16x16x32_bf16(al, bh, acc, 0, 0, 0);
                        acc = __builtin_amdgcn_mfma_f32_16x16x32_bf16(ah, bl, acc, 0, 0, 0);
                    }
                    if (wg < 128) {
#pragma unroll
                        for (int r = 0; r < 4; ++r) {
                            int grow = rt3 * 16 + kg * 4 + r;
                            o2a[grow * 256 + col] = acc[r];
                        }
                    } else {
                        float bb2 = bs1[col];
#pragma unroll
                        for (int r = 0; r < 4; ++r) {
                            int grow = rt3 * 16 + kg * 4 + r;
                            int b0 = grow >> 6, j = grow & 63;
                            tST[(b0 * 256 + col) * 64 + j] = acc[r] + bb2;
                        }
                    }
                }
            }

            // barrier
            { ++bargen; unsigned tgt = 256u * bargen;
              __syncthreads();
              if (tid == 0) { __threadfence(); atomicAdd(cnt, 1u);
                  for (long it = 0; it < (1L << 24); ++it) { if (atomicAdd(cnt, 0u) >= tgt) break; __builtin_amdgcn_s_sleep(2); }
                  __threadfence(); }
              __syncthreads(); }
        }
    }

    // ===== scores phase: 2 rows per WG =====
    {
        int halfh = tid >> 7, rr = (tid >> 6) & 1, j = tid & 63;
        int row = wg * 2 + rr;
        int bq = row >> 6;
        const float* rs = rS + row * 256 + halfh * 128;
        const float* ts = tST + bq * 16384 + halfh * 128 * 64 + j;
        float acc = 0.f;
        for (int h2 = 0; h2 < 128; ++h2)
            acc += fmaxf(rs[h2] + ts[h2 * 64], 0.f) * Ws2[halfh * 128 + h2];
        ssum[tid] = acc;
        __syncthreads();
        if (halfh == 0)
            scores[row * 64 + j] = ssum[tid] + ssum[tid + 128] + bs2[0];
    }
}

// ---- 4. sinkhorn (unchanged) ----
__global__ __launch_bounds__(1024) void k_sinkhorn(const float* __restrict__ scores,
                                                   float* __restrict__ probs) {
    int b = blockIdx.x;
    int t = threadIdx.x;
    int j = t & 63, rg = t >> 6;
    float v[4];
    const float* src = scores + b * 4096 + rg * 256 + j;
#pragma unroll
    for (int k = 0; k < 4; ++k) v[k] = src[k * 64];

    __shared__ float lm_s[2][16][64];
    __shared__ float ps_s[2][16][64];

    for (int it = 0; it < 10; ++it) {
#pragma unroll
        for (int k = 0; k < 4; ++k) {
            float m = v[k];
#pragma unroll
            for (int s = 1; s < 64; s <<= 1) m = fmaxf(m, __shfl_xor(m, s));
            float e = __expf(v[k] - m), ss = e;
#pragma unroll
            for (int s = 1; s < 64; s <<= 1) ss += __shfl_xor(ss, s);
            v[k] -= m + __logf(ss);
        }
        int p = it & 1;
        float lm = fmaxf(fmaxf(v[0], v[1]), fmaxf(v[2], v[3]));
        float ps = __expf(v[0] - lm) + __expf(v[1] - lm) + __expf(v[2] - lm) + __expf(v[3] - lm);
        lm_s[p][rg][j] = lm; ps_s[p][rg][j] = ps;
        __syncthreads();
        float M = lm_s[p][0][j];
#pragma unroll
        for (int g2 = 1; g2 < 16; ++g2) M = fmaxf(M, lm_s[p][g2][j]);
        float S = 0.f;
#pragma unroll
        for (int g2 = 0; g2 < 16; ++g2) S += ps_s[p][g2][j] * __expf(lm_s[p][g2][j] - M);
        float lse = M + __logf(S);
#pragma unroll
        for (int k = 0; k < 4; ++k) v[k] -= lse;
    }
    float* dst = probs + b * 4096 + rg * 256 + j;
#pragma unroll
    for (int k = 0; k < 4; ++k) dst[k * 64] = __expf(v[k]);
}

extern "C" void kernel_launch(void* const* d_in, const int* in_sizes, int n_in,
                              void* d_out, int out_size, void* d_ws, size_t ws_size,
                              hipStream_t stream) {
    const float* robot_raw = (const float*)d_in[0];
    const float* edge_raw  = (const float*)d_in[1];
    const float* Wp    = (const float*)d_in[2];
    const float* bp    = (const float*)d_in[3];
    const float* W_r2t = (const float*)d_in[4];
    const float* b_r2t = (const float*)d_in[5];
    const float* W_pt  = (const float*)d_in[6];
    const float* b_pt  = (const float*)d_in[7];
    const float* g_t   = (const float*)d_in[8];
    const float* be_t  = (const float*)d_in[9];
    const float* W_t2r = (const float*)d_in[10];
    const float* b_t2r = (const float*)d_in[11];
    const float* W_pr  = (const float*)d_in[12];
    const float* b_pr  = (const float*)d_in[13];
    const float* g_r   = (const float*)d_in[14];
    const float* be_r  = (const float*)d_in[15];
    const float* Ws1   = (const float*)d_in[16];
    const float* bs1   = (const float*)d_in[17];
    const float* Ws2   = (const float*)d_in[18];
    const float* bs2   = (const float*)d_in[19];

    char* ws = (char*)d_ws;
    unsigned short* edge_bf = (unsigned short*)(ws);            // 8,388,608
    float* traw     = (float*)(ws + 8388608);                   //   262,144
    float* robot_h  = (float*)(ws + 8650752);                   //   524,288
    float* target_h = (float*)(ws + 9175040);                   //   524,288
    unsigned short* WcT = (unsigned short*)(ws + 9699328);      //   393,216
    float* bc       = (float*)(ws + 10092544);                  //     6,144
    float* rWa      = (float*)(ws + 10098688);                  //   524,288
    float* tWa      = (float*)(ws + 10622976);                  //   524,288
    float* agg      = (float*)(ws + 11147264);                  //   524,288
    float* rS       = (float*)(ws + 11671552);                  //   524,288
    float* tST      = (float*)(ws + 12195840);                  //   524,288
    unsigned short* WTbig = (unsigned short*)(ws + 12720128);   // 3,145,728
    unsigned short* WT2   = (unsigned short*)(ws + 15865856);   // 1,835,008
    unsigned short* yhi   = (unsigned short*)(ws + 17700864);   //   262,144
    unsigned short* ylo   = (unsigned short*)(ws + 17963008);   //   262,144
    float* parts    = (float*)(ws + 18225152);                  //    65,536
    unsigned* cnt   = (unsigned*)(ws + 18290688);               //         4

    float* out    = (float*)d_out;
    float* probs  = out;            // output 0
    float* scores = out + 32768;    // output 1

    hipMemsetAsync(cnt, 0, 4, stream);
    hipLaunchKernelGGL(k_prep_w, dim3(4614), dim3(256), 0, stream,
                       edge_raw, edge_bf, traw,
                       Wp, bp, W_r2t, b_r2t, W_t2r, b_t2r, W_pt, W_pr, Ws1, WcT, bc, WTbig, WT2);
    hipLaunchKernelGGL(k_proj, dim3(512), dim3(256), 0, stream,
                       robot_raw, traw, Wp, bp, W_r2t, robot_h, target_h, rWa);
    hipLaunchKernelGGL(k_layers, dim3(256), dim3(256), 0, stream,
                       edge_bf, WcT, bc, rWa, tWa, agg, robot_h, target_h,
                       WTbig, WT2, yhi, ylo, parts, cnt,
                       b_pt, b_pr, g_t, g_r, be_t, be_r, bs1,
                       rS, tST, Ws2, bs2, scores);
    hipLaunchKernelGGL(k_sinkhorn, dim3(8), dim3(1024), 0, stream, scores, probs);
}

// Round 9
// 364.512 us; speedup vs baseline: 2.0154x; 2.0154x over previous
//
#include <hip/hip_runtime.h>

// NavAssignNet on MI355X — round 9: revert to round-7 structure (best: 321us),
// plus: bigpass split into 1024 WGs (2x occupancy) with LDS-staged rowbias
// epilogue (64 scalar loads/thread -> 8 float4 + 32 ds_reads), and k_scores
// fused into k_sinkhorn. Mega-kernel (round 8, 734us) abandoned: software grid
// barriers at 1 WG/CU cost ~25us each vs ~3us dispatch gaps.

typedef short bf16x8 __attribute__((ext_vector_type(8)));
typedef float f32x4 __attribute__((ext_vector_type(4)));

#define DEV static __device__ __forceinline__

DEV unsigned short f2bf(float x) {
    unsigned u = __float_as_uint(x);
    return (unsigned short)((u + 0x7fffu + ((u >> 16) & 1u)) >> 16);
}
DEV void split2(float v, unsigned short& hi, unsigned short& lo) {
    unsigned short h = f2bf(v);
    float fh = __uint_as_float(((unsigned)h) << 16);
    hi = h;
    lo = f2bf(v - fh);
}

// ---- 1. prep+weights ----
__global__ __launch_bounds__(256) void k_prep_w(const float* __restrict__ edge,
                                                unsigned short* __restrict__ edge_bf,
                                                float* __restrict__ traw,
                                                const float* __restrict__ Wp,
                                                const float* __restrict__ bp,
                                                const float* __restrict__ W_r2t,
                                                const float* __restrict__ b_r2t,
                                                const float* __restrict__ W_t2r,
                                                const float* __restrict__ b_t2r,
                                                const float* __restrict__ W_pt,
                                                const float* __restrict__ W_pr,
                                                const float* __restrict__ Ws1,
                                                unsigned short* __restrict__ WcT,
                                                float* __restrict__ bc,
                                                unsigned short* __restrict__ WTbig,
                                                unsigned short* __restrict__ WT2) {
    if (blockIdx.x < 512) {
        int wg = blockIdx.x;
        int b = wg >> 6, j = wg & 63;
        int t = threadIdx.x;
        int d = t & 127, ih = t >> 7;
        float s = 0.f;
        long base = ((long)(b * 64 + ih * 32) * 64 + j) * 128 + d;
#pragma unroll 8
        for (int ii = 0; ii < 32; ++ii) {
            long idx = base + (long)ii * 8192;
            float v = edge[idx];
            s += v;
            edge_bf[idx] = f2bf(v);
        }
        __shared__ float part[128];
        if (ih == 1) part[d] = s;
        __syncthreads();
        if (ih == 0) traw[(b * 64 + j) * 128 + d] = (s + part[d]) * (1.f / 64.f);
        return;
    }
    int blk0 = blockIdx.x - 512;
    int h = threadIdx.x;
    if (blk0 < 774) {
        int blk = blk0;
        if (blk < 768) {
            int p = blk >> 7, d = blk & 127, l = p >> 1;
            const float* Wb = ((p & 1) ? W_t2r : W_r2t) + l * 512 * 256 + 256 * 256;
            float acc = 0.f;
            for (int k = 0; k < 256; ++k) acc += Wp[d * 256 + k] * Wb[k * 256 + h];
            WcT[p * 32768 + h * 128 + d] = f2bf(acc);
        } else {
            int p = blk - 768, l = p >> 1;
            const float* Wb = ((p & 1) ? W_t2r : W_r2t) + l * 512 * 256 + 256 * 256;
            const float* bm = ((p & 1) ? b_t2r : b_r2t) + l * 256;
            float acc = bm[h];
            for (int k = 0; k < 256; ++k) acc += bp[k] * Wb[k * 256 + h];
            bc[p * 256 + h] = acc;
        }
        return;
    }
    int blk = blk0 - 774, t = threadIdx.x;
    if (blk < 1536) {
        int mat = blk >> 8, hh = blk & 255, l = mat >> 1;
        const float* W = ((mat & 1) ? W_pr : W_pt) + l * 512 * 256;
        unsigned short* dh = WTbig + mat * 262144 + hh * 512;
        unsigned short* dl = dh + 131072;
        for (int k = t; k < 512; k += 256) {
            unsigned short hi, lo;
            split2(W[k * 256 + hh], hi, lo);
            dh[k] = hi; dl[k] = lo;
        }
    } else {
        int m2 = blk - 1536, mat = m2 >> 8, hh = m2 & 255;
        const float* W;
        if (mat == 6) W = Ws1 + 256 * 256;
        else if (mat == 5) W = Ws1;
        else if (mat & 1) W = W_r2t + ((mat >> 1) + 1) * 512 * 256;
        else W = W_t2r + (mat >> 1) * 512 * 256;
        unsigned short* dh = WT2 + mat * 131072 + hh * 256;
        unsigned short* dl = dh + 65536;
        unsigned short hi, lo;
        split2(W[t * 256 + hh], hi, lo);
        dh[t] = hi; dl[t] = lo;
    }
}

// ---- 2. proj ----
__global__ __launch_bounds__(256) void k_proj(const float* __restrict__ robot_raw,
                                              const float* __restrict__ traw,
                                              const float* __restrict__ Wp,
                                              const float* __restrict__ bp,
                                              const float* __restrict__ Wa0,
                                              float* __restrict__ robot_h,
                                              float* __restrict__ target_h,
                                              float* __restrict__ rWa) {
    int h = threadIdx.x;
    int r0 = blockIdx.x * 2;
    int robot = (r0 < 512);
    const float* in;
    float* out;
    if (robot) { in = robot_raw + r0 * 128; out = robot_h + r0 * 256; }
    else       { in = traw + (r0 - 512) * 128; out = target_h + (r0 - 512) * 256; }
    float a0 = 0, a1 = 0;
    for (int k = 0; k < 128; ++k) {
        float w = Wp[k * 256 + h];
        a0 += in[k] * w; a1 += in[128 + k] * w;
    }
    float b = bp[h];
    a0 += b; a1 += b;
    out[h] = a0; out[256 + h] = a1;

    __shared__ float yl[2][257];
    if (robot) { yl[0][h] = a0; yl[1][h] = a1; }
    __syncthreads();
    if (robot) {
        float c0 = 0, c1 = 0;
        for (int k = 0; k < 256; ++k) {
            float w = Wa0[k * 256 + h];
            c0 += yl[0][k] * w; c1 += yl[1][k] * w;
        }
        rWa[r0 * 256 + h] = c0; rWa[(r0 + 1) * 256 + h] = c1;
    }
}

// ---- 3. update via MFMA split-bf16, 1024 threads / 16 waves (round 7 version) ----
__global__ __launch_bounds__(1024) void k_update_mfma(
        float* __restrict__ state, const float* __restrict__ agg,
        const unsigned short* __restrict__ WTm,   // [hi 256x512][lo 256x512]
        const float* __restrict__ bvec, const float* __restrict__ g, const float* __restrict__ be,
        const unsigned short* __restrict__ WT2a,  // [hi 256x256][lo 256x256]
        float* __restrict__ out2a,
        const unsigned short* __restrict__ WT2b, const float* __restrict__ b2b,
        float* __restrict__ out2b) {
    int r0 = blockIdx.x * 16;
    int t = threadIdx.x;
    int w = t >> 6, lane = t & 63;
    int c16 = lane & 15, kg = lane >> 4;
    int col = (w << 4) | c16;

    __shared__ unsigned short Ahi[16 * 512];
    __shared__ unsigned short Alo[16 * 512];
    __shared__ unsigned short Yhi[16 * 256];
    __shared__ unsigned short Ylo[16 * 256];
    __shared__ float red[16][16][2];

    {
        int row = t & 15, kq = t >> 4;   // kq 0..63 -> 8 K-elems each
        const float* src = (kq < 32) ? (state + (r0 + row) * 256 + kq * 8)
                                     : (agg + (r0 + row) * 256 + (kq - 32) * 8);
        float4 a = *(const float4*)(src);
        float4 b2 = *(const float4*)(src + 4);
        unsigned short h[8], lo[8];
        split2(a.x, h[0], lo[0]); split2(a.y, h[1], lo[1]);
        split2(a.z, h[2], lo[2]); split2(a.w, h[3], lo[3]);
        split2(b2.x, h[4], lo[4]); split2(b2.y, h[5], lo[5]);
        split2(b2.z, h[6], lo[6]); split2(b2.w, h[7], lo[7]);
        int byte = row * 1024 + kq * 16;
        byte ^= (row & 7) << 4;
        ushort4* ph = (ushort4*)((char*)Ahi + byte);
        ph[0] = make_ushort4(h[0], h[1], h[2], h[3]);
        ph[1] = make_ushort4(h[4], h[5], h[6], h[7]);
        ushort4* pl = (ushort4*)((char*)Alo + byte);
        pl[0] = make_ushort4(lo[0], lo[1], lo[2], lo[3]);
        pl[1] = make_ushort4(lo[4], lo[5], lo[6], lo[7]);
    }
    __syncthreads();

    f32x4 acc = f32x4{0.f, 0.f, 0.f, 0.f};
    const unsigned short* Bh0 = WTm + col * 512 + kg * 8;
#pragma unroll 4
    for (int ks = 0; ks < 16; ++ks) {
        int ab = c16 * 1024 + ks * 64 + kg * 16;
        ab ^= (c16 & 7) << 4;
        bf16x8 ah = *(const bf16x8*)((const char*)Ahi + ab);
        bf16x8 al = *(const bf16x8*)((const char*)Alo + ab);
        const unsigned short* p = Bh0 + ks * 32;
        bf16x8 bh = *(const bf16x8*)p;
        bf16x8 bl = *(const bf16x8*)(p + 131072);
        acc = __builtin_amdgcn_mfma_f32_16x16x32_bf16(ah, bh, acc, 0, 0, 0);
        acc = __builtin_amdgcn_mfma_f32_16x16x32_bf16(al, bh, acc, 0, 0, 0);
        acc = __builtin_amdgcn_mfma_f32_16x16x32_bf16(ah, bl, acc, 0, 0, 0);
    }

    float x[4];
    {
        float bv = bvec[col];
#pragma unroll
        for (int r = 0; r < 4; ++r) {
            int row = kg * 4 + r;
            x[r] = acc[r] + state[(r0 + row) * 256 + col] + bv;
        }
    }

    float s[4], q[4];
#pragma unroll
    for (int r = 0; r < 4; ++r) {
        s[r] = x[r];
        q[r] = x[r] * x[r];
#pragma unroll
        for (int m = 1; m < 16; m <<= 1) {
            s[r] += __shfl_xor(s[r], m);
            q[r] += __shfl_xor(q[r], m);
        }
    }
    if (c16 == 0) {
#pragma unroll
        for (int r = 0; r < 4; ++r) {
            red[w][kg * 4 + r][0] = s[r];
            red[w][kg * 4 + r][1] = q[r];
        }
    }
    __syncthreads();
    float mr[4], rsr[4];
#pragma unroll
    for (int r = 0; r < 4; ++r) {
        int row = kg * 4 + r;
        float S = 0.f, Q = 0.f;
#pragma unroll
        for (int w2 = 0; w2 < 16; ++w2) { S += red[w2][row][0]; Q += red[w2][row][1]; }
        float m = S * (1.f / 256.f);
        float v = Q * (1.f / 256.f) - m * m;
        mr[r] = m;
        rsr[r] = rsqrtf(v + 1e-5f);
    }

    {
        float gg = g[col], bb = be[col];
#pragma unroll
        for (int r = 0; r < 4; ++r) {
            int row = kg * 4 + r;
            float y = (x[r] - mr[r]) * rsr[r] * gg + bb;
            state[(r0 + row) * 256 + col] = y;
            unsigned short yh, yl2;
            split2(y, yh, yl2);
            int byte = (row * 512 + col * 2) ^ ((row & 7) << 4);
            *(unsigned short*)((char*)Yhi + byte) = yh;
            *(unsigned short*)((char*)Ylo + byte) = yl2;
        }
    }
    __syncthreads();

    f32x4 acc2 = f32x4{0.f, 0.f, 0.f, 0.f};
    f32x4 acc3 = f32x4{0.f, 0.f, 0.f, 0.f};
    const unsigned short* B2h0 = WT2a + col * 256 + kg * 8;
    const unsigned short* B3h0 = WT2b ? (WT2b + col * 256 + kg * 8) : B2h0;
    int haveB = (WT2b != nullptr);
#pragma unroll 4
    for (int ks = 0; ks < 8; ++ks) {
        int ab = c16 * 512 + ks * 64 + kg * 16;
        ab ^= (c16 & 7) << 4;
        bf16x8 ah = *(const bf16x8*)((const char*)Yhi + ab);
        bf16x8 al = *(const bf16x8*)((const char*)Ylo + ab);
        const unsigned short* p = B2h0 + ks * 32;
        bf16x8 bh = *(const bf16x8*)p;
        bf16x8 bl = *(const bf16x8*)(p + 65536);
        acc2 = __builtin_amdgcn_mfma_f32_16x16x32_bf16(ah, bh, acc2, 0, 0, 0);
        acc2 = __builtin_amdgcn_mfma_f32_16x16x32_bf16(al, bh, acc2, 0, 0, 0);
        acc2 = __builtin_amdgcn_mfma_f32_16x16x32_bf16(ah, bl, acc2, 0, 0, 0);
        if (haveB) {
            const unsigned short* p3 = B3h0 + ks * 32;
            bf16x8 bh3 = *(const bf16x8*)p3;
            bf16x8 bl3 = *(const bf16x8*)(p3 + 65536);
            acc3 = __builtin_amdgcn_mfma_f32_16x16x32_bf16(ah, bh3, acc3, 0, 0, 0);
            acc3 = __builtin_amdgcn_mfma_f32_16x16x32_bf16(al, bh3, acc3, 0, 0, 0);
            acc3 = __builtin_amdgcn_mfma_f32_16x16x32_bf16(ah, bl3, acc3, 0, 0, 0);
        }
    }
#pragma unroll
    for (int r = 0; r < 4; ++r) {
        int row = kg * 4 + r;
        out2a[(r0 + row) * 256 + col] = acc2[r];
    }
    if (haveB) {
        float bb2 = b2b[col];
#pragma unroll
        for (int r = 0; r < 4; ++r) {
            int grow = r0 + kg * 4 + r;
            int b0 = grow >> 6, j = grow & 63;
            out2b[(b0 * 256 + col) * 64 + j] = acc3[r] + bb2;
        }
    }
}

// ---- 4. bigpass: 1024 WGs (tile = bid>>1, col-half = bid&1), LDS rowbias ----
__global__ __launch_bounds__(256) void k_bigpass(const unsigned short* __restrict__ edge_bf,
                                                 const unsigned short* __restrict__ WcT,
                                                 const float* __restrict__ bc,
                                                 const float* __restrict__ rowbias,
                                                 float* __restrict__ agg,
                                                 int mode,
                                                 const unsigned short* __restrict__ prefA,
                                                 const unsigned short* __restrict__ prefB,
                                                 int nb) {            // nb = uint4 count of B slice
    int bid = blockIdx.x;
    int tile = bid >> 1, nh = bid & 1;   // tile = b*64 + jj; nh = col half
    int b = tile >> 6, jj = tile & 63;
    int w = threadIdx.x >> 6, lane = threadIdx.x & 63;
    int c16 = lane & 15, kgrp = lane >> 4;

    __shared__ float rbl[64 * 132];      // 64 rows x 128 cols, stride 132 (pad)

    // stage rowbias[b*64 .. +63][nh*128 .. +127] into LDS (vectorized)
    {
        const float* rbsrc = rowbias + (b * 64) * 256 + nh * 128;
#pragma unroll
        for (int k = 0; k < 8; ++k) {
            int f = k * 256 + threadIdx.x;   // 0..2047 float4 slots
            int row = f >> 5, c4 = f & 31;
            float4 vv = *(const float4*)(rbsrc + row * 256 + c4 * 4);
            *(float4*)(&rbl[row * 132 + c4 * 4]) = vv;
        }
    }

    int rstride = (mode == 0) ? 8192 : 128;
    const unsigned short* Ap = edge_bf + b * 524288 + ((mode == 0) ? jj * 128 : jj * 8192)
                             + c16 * rstride + 8 * kgrp;
    const unsigned short* Bp = WcT + (nh * 128 + w * 32 + c16) * 128 + 8 * kgrp;

    bf16x8 av[4][4], bv[2][4];
#pragma unroll
    for (int kk = 0; kk < 4; ++kk) {
#pragma unroll
        for (int mi = 0; mi < 4; ++mi)
            av[mi][kk] = *(const bf16x8*)(Ap + mi * 16 * rstride + kk * 32);
#pragma unroll
        for (int ni = 0; ni < 2; ++ni)
            bv[ni][kk] = *(const bf16x8*)(Bp + ni * 2048 + kk * 32);
    }
    __builtin_amdgcn_sched_barrier(0);

    f32x4 acc[4][2];
#pragma unroll
    for (int mi = 0; mi < 4; ++mi)
#pragma unroll
        for (int ni = 0; ni < 2; ++ni) acc[mi][ni] = f32x4{0.f, 0.f, 0.f, 0.f};
#pragma unroll
    for (int kk = 0; kk < 4; ++kk)
#pragma unroll
        for (int mi = 0; mi < 4; ++mi)
#pragma unroll
            for (int ni = 0; ni < 2; ++ni)
                acc[mi][ni] = __builtin_amdgcn_mfma_f32_16x16x32_bf16(av[mi][kk], bv[ni][kk], acc[mi][ni], 0, 0, 0);

    // issue prefetch loads (next update's weights) to overlap epilogue
    int s = (bid >> 4) & 63;
    const uint4* pa = (const uint4*)prefA + (long)s * 512;
    const uint4* pb = (const uint4*)prefB + (long)s * nb;
    uint4 pf0 = pa[threadIdx.x];
    uint4 pf1 = pa[threadIdx.x + 256];
    uint4 pf2 = pb[threadIdx.x];
    uint4 pf3, pf4;
    int big = (nb > 256);
    if (big) { pf3 = pb[threadIdx.x + 256]; pf4 = pb[threadIdx.x + 512]; }
    __builtin_amdgcn_sched_barrier(0);

    __syncthreads();   // rowbias staged

    float colsum[2] = {0.f, 0.f};
#pragma unroll
    for (int ni = 0; ni < 2; ++ni) {
        int colL = w * 32 + ni * 16 + c16;
        float bch = bc[nh * 128 + colL];
#pragma unroll
        for (int mi = 0; mi < 4; ++mi) {
            int rbase = 16 * mi + 4 * kgrp;
#pragma unroll
            for (int r = 0; r < 4; ++r) {
                float v = acc[mi][ni][r] + rbl[(rbase + r) * 132 + colL] + bch;
                colsum[ni] += fmaxf(v, 0.f);
            }
        }
    }
#pragma unroll
    for (int ni = 0; ni < 2; ++ni) {
        colsum[ni] += __shfl_xor(colsum[ni], 16);
        colsum[ni] += __shfl_xor(colsum[ni], 32);
    }
    if (kgrp == 0) {
        float* o = agg + (b * 64 + jj) * 256 + nh * 128 + w * 32 + c16;
#pragma unroll
        for (int ni = 0; ni < 2; ++ni) o[16 * ni] = colsum[ni] * (1.f / 64.f);
    }

    unsigned accp = pf0.x ^ pf0.w ^ pf1.y ^ pf2.z;
    if (big) accp ^= pf3.x ^ pf4.w;
    asm volatile("" :: "v"(accp));
}

// ---- 5. sinkhorn with fused scores phase ----
__global__ __launch_bounds__(1024) void k_sinkhorn(const float* __restrict__ rS,
                                                   const float* __restrict__ tST,
                                                   const float* __restrict__ Ws2,
                                                   const float* __restrict__ bs2,
                                                   float* __restrict__ scores,
                                                   float* __restrict__ probs) {
    int b = blockIdx.x;
    int t = threadIdx.x;
    int j = t & 63, rg = t >> 6;         // rows rg*4 .. rg*4+3

    // phase 0: scores[b, i, j] = sum_h relu(rS[b,i,h] + tST[b,h,j]) * Ws2[h] + bs2
    float v[4];
    {
        const float* rs0 = rS + (b * 64 + rg * 4) * 256;   // wave-uniform rows
        const float* ts = tST + b * 16384 + j;             // coalesced over lanes
        float a0 = 0.f, a1 = 0.f, a2 = 0.f, a3 = 0.f;
        for (int h = 0; h < 256; ++h) {
            float tv = ts[h * 64];
            float wv = Ws2[h];
            a0 += fmaxf(rs0[h] + tv, 0.f) * wv;
            a1 += fmaxf(rs0[256 + h] + tv, 0.f) * wv;
            a2 += fmaxf(rs0[512 + h] + tv, 0.f) * wv;
            a3 += fmaxf(rs0[768 + h] + tv, 0.f) * wv;
        }
        float bb = bs2[0];
        v[0] = a0 + bb; v[1] = a1 + bb; v[2] = a2 + bb; v[3] = a3 + bb;
        float* so = scores + (b * 64 + rg * 4) * 64 + j;
#pragma unroll
        for (int k = 0; k < 4; ++k) so[k * 64] = v[k];
    }

    __shared__ float lm_s[2][16][64];
    __shared__ float ps_s[2][16][64];

    for (int it = 0; it < 10; ++it) {
#pragma unroll
        for (int k = 0; k < 4; ++k) {
            float m = v[k];
#pragma unroll
            for (int s = 1; s < 64; s <<= 1) m = fmaxf(m, __shfl_xor(m, s));
            float e = __expf(v[k] - m), ss = e;
#pragma unroll
            for (int s = 1; s < 64; s <<= 1) ss += __shfl_xor(ss, s);
            v[k] -= m + __logf(ss);
        }
        int p = it & 1;
        float lm = fmaxf(fmaxf(v[0], v[1]), fmaxf(v[2], v[3]));
        float ps = __expf(v[0] - lm) + __expf(v[1] - lm) + __expf(v[2] - lm) + __expf(v[3] - lm);
        lm_s[p][rg][j] = lm; ps_s[p][rg][j] = ps;
        __syncthreads();
        float M = lm_s[p][0][j];
#pragma unroll
        for (int g2 = 1; g2 < 16; ++g2) M = fmaxf(M, lm_s[p][g2][j]);
        float S = 0.f;
#pragma unroll
        for (int g2 = 0; g2 < 16; ++g2) S += ps_s[p][g2][j] * __expf(lm_s[p][g2][j] - M);
        float lse = M + __logf(S);
#pragma unroll
        for (int k = 0; k < 4; ++k) v[k] -= lse;
    }
    float* dst = probs + b * 4096 + rg * 256 + j;
#pragma unroll
    for (int k = 0; k < 4; ++k) dst[k * 64] = __expf(v[k]);
}

extern "C" void kernel_launch(void* const* d_in, const int* in_sizes, int n_in,
                              void* d_out, int out_size, void* d_ws, size_t ws_size,
                              hipStream_t stream) {
    const float* robot_raw = (const float*)d_in[0];
    const float* edge_raw  = (const float*)d_in[1];
    const float* Wp    = (const float*)d_in[2];
    const float* bp    = (const float*)d_in[3];
    const float* W_r2t = (const float*)d_in[4];
    const float* b_r2t = (const float*)d_in[5];
    const float* W_pt  = (const float*)d_in[6];
    const float* b_pt  = (const float*)d_in[7];
    const float* g_t   = (const float*)d_in[8];
    const float* be_t  = (const float*)d_in[9];
    const float* W_t2r = (const float*)d_in[10];
    const float* b_t2r = (const float*)d_in[11];
    const float* W_pr  = (const float*)d_in[12];
    const float* b_pr  = (const float*)d_in[13];
    const float* g_r   = (const float*)d_in[14];
    const float* be_r  = (const float*)d_in[15];
    const float* Ws1   = (const float*)d_in[16];
    const float* bs1   = (const float*)d_in[17];
    const float* Ws2   = (const float*)d_in[18];
    const float* bs2   = (const float*)d_in[19];

    char* ws = (char*)d_ws;
    unsigned short* edge_bf = (unsigned short*)(ws);            // 8,388,608
    float* traw     = (float*)(ws + 8388608);                   //   262,144
    float* robot_h  = (float*)(ws + 8650752);                   //   524,288
    float* target_h = (float*)(ws + 9175040);                   //   524,288
    unsigned short* WcT = (unsigned short*)(ws + 9699328);      //   393,216
    float* bc       = (float*)(ws + 10092544);                  //     6,144
    float* rWa      = (float*)(ws + 10098688);                  //   524,288
    float* tWa      = (float*)(ws + 10622976);                  //   524,288
    float* agg      = (float*)(ws + 11147264);                  //   524,288
    float* rS       = (float*)(ws + 11671552);                  //   524,288
    float* tST      = (float*)(ws + 12195840);                  //   524,288
    unsigned short* WTbig = (unsigned short*)(ws + 12720128);   // 3,145,728
    unsigned short* WT2   = (unsigned short*)(ws + 15865856);   // 1,835,008

    float* out    = (float*)d_out;
    float* probs  = out;            // output 0
    float* scores = out + 32768;    // output 1

    hipLaunchKernelGGL(k_prep_w, dim3(4614), dim3(256), 0, stream,
                       edge_raw, edge_bf, traw,
                       Wp, bp, W_r2t, b_r2t, W_t2r, b_t2r, W_pt, W_pr, Ws1, WcT, bc, WTbig, WT2);
    hipLaunchKernelGGL(k_proj, dim3(512), dim3(256), 0, stream,
                       robot_raw, traw, Wp, bp, W_r2t, robot_h, target_h, rWa);

    for (int l = 0; l < 3; ++l) {
        // r2t bigpass + prefetch of the target-update weights
        {
            const unsigned short* pA = WTbig + (2 * l) * 262144;
            const unsigned short* pB = WT2 + (2 * l) * 131072;
            int nb = (l == 2) ? 768 : 256;                     // l==2 covers mats 4..6
            hipLaunchKernelGGL(k_bigpass, dim3(1024), dim3(256), 0, stream,
                               edge_bf, WcT + (2 * l) * 32768, bc + (2 * l) * 256, rWa, agg, 0,
                               pA, pB, nb);
        }
        const unsigned short* W2b = (l == 2) ? (WT2 + 6 * 131072) : nullptr;
        const float* b2b = (l == 2) ? bs1 : nullptr;
        float* o2b = (l == 2) ? tST : nullptr;
        hipLaunchKernelGGL(k_update_mfma, dim3(32), dim3(1024), 0, stream,
                           target_h, agg, WTbig + (2 * l) * 262144,
                           b_pt + l * 256, g_t + l * 256, be_t + l * 256,
                           WT2 + (2 * l) * 131072, tWa, W2b, b2b, o2b);
        // t2r bigpass + prefetch of the robot-update weights
        {
            const unsigned short* pA = WTbig + (2 * l + 1) * 262144;
            int m2 = (l < 2) ? (2 * l + 1) : 5;
            const unsigned short* pB = WT2 + m2 * 131072;
            hipLaunchKernelGGL(k_bigpass, dim3(1024), dim3(256), 0, stream,
                               edge_bf, WcT + (2 * l + 1) * 32768, bc + (2 * l + 1) * 256, tWa, agg, 1,
                               pA, pB, 256);
        }
        const unsigned short* W2a = (l < 2) ? (WT2 + (2 * l + 1) * 131072) : (WT2 + 5 * 131072);
        float* o2a = (l < 2) ? rWa : rS;
        hipLaunchKernelGGL(k_update_mfma, dim3(32), dim3(1024), 0, stream,
                           robot_h, agg, WTbig + (2 * l + 1) * 262144,
                           b_pr + l * 256, g_r + l * 256, be_r + l * 256,
                           W2a, o2a, (const unsigned short*)nullptr, (const float*)nullptr, (float*)nullptr);
    }

    hipLaunchKernelGGL(k_sinkhorn, dim3(8), dim3(1024), 0, stream,
                       rS, tST, Ws2, bs2, scores, probs);
}

// Round 10
// 342.457 us; speedup vs baseline: 2.1452x; 1.0644x over previous
//
#include <hip/hip_runtime.h>

// NavAssignNet on MI355X — round 10: round 9 minus the scores->sinkhorn fusion
// (fusing put the scores GEMV on an 8-WG grid: 65us pure-latency; separate
// 128-WG k_scores was invisible). Keep: 1024-WG bigpass + LDS rowbias,
// 16-wave updates, distributed prefetch, merged prep+weights.

typedef short bf16x8 __attribute__((ext_vector_type(8)));
typedef float f32x4 __attribute__((ext_vector_type(4)));

#define DEV static __device__ __forceinline__

DEV unsigned short f2bf(float x) {
    unsigned u = __float_as_uint(x);
    return (unsigned short)((u + 0x7fffu + ((u >> 16) & 1u)) >> 16);
}
DEV void split2(float v, unsigned short& hi, unsigned short& lo) {
    unsigned short h = f2bf(v);
    float fh = __uint_as_float(((unsigned)h) << 16);
    hi = h;
    lo = f2bf(v - fh);
}

// ---- 1. prep+weights ----
__global__ __launch_bounds__(256) void k_prep_w(const float* __restrict__ edge,
                                                unsigned short* __restrict__ edge_bf,
                                                float* __restrict__ traw,
                                                const float* __restrict__ Wp,
                                                const float* __restrict__ bp,
                                                const float* __restrict__ W_r2t,
                                                const float* __restrict__ b_r2t,
                                                const float* __restrict__ W_t2r,
                                                const float* __restrict__ b_t2r,
                                                const float* __restrict__ W_pt,
                                                const float* __restrict__ W_pr,
                                                const float* __restrict__ Ws1,
                                                unsigned short* __restrict__ WcT,
                                                float* __restrict__ bc,
                                                unsigned short* __restrict__ WTbig,
                                                unsigned short* __restrict__ WT2) {
    if (blockIdx.x < 512) {
        int wg = blockIdx.x;
        int b = wg >> 6, j = wg & 63;
        int t = threadIdx.x;
        int d = t & 127, ih = t >> 7;
        float s = 0.f;
        long base = ((long)(b * 64 + ih * 32) * 64 + j) * 128 + d;
#pragma unroll 8
        for (int ii = 0; ii < 32; ++ii) {
            long idx = base + (long)ii * 8192;
            float v = edge[idx];
            s += v;
            edge_bf[idx] = f2bf(v);
        }
        __shared__ float part[128];
        if (ih == 1) part[d] = s;
        __syncthreads();
        if (ih == 0) traw[(b * 64 + j) * 128 + d] = (s + part[d]) * (1.f / 64.f);
        return;
    }
    int blk0 = blockIdx.x - 512;
    int h = threadIdx.x;
    if (blk0 < 774) {
        int blk = blk0;
        if (blk < 768) {
            int p = blk >> 7, d = blk & 127, l = p >> 1;
            const float* Wb = ((p & 1) ? W_t2r : W_r2t) + l * 512 * 256 + 256 * 256;
            float acc = 0.f;
            for (int k = 0; k < 256; ++k) acc += Wp[d * 256 + k] * Wb[k * 256 + h];
            WcT[p * 32768 + h * 128 + d] = f2bf(acc);
        } else {
            int p = blk - 768, l = p >> 1;
            const float* Wb = ((p & 1) ? W_t2r : W_r2t) + l * 512 * 256 + 256 * 256;
            const float* bm = ((p & 1) ? b_t2r : b_r2t) + l * 256;
            float acc = bm[h];
            for (int k = 0; k < 256; ++k) acc += bp[k] * Wb[k * 256 + h];
            bc[p * 256 + h] = acc;
        }
        return;
    }
    int blk = blk0 - 774, t = threadIdx.x;
    if (blk < 1536) {
        int mat = blk >> 8, hh = blk & 255, l = mat >> 1;
        const float* W = ((mat & 1) ? W_pr : W_pt) + l * 512 * 256;
        unsigned short* dh = WTbig + mat * 262144 + hh * 512;
        unsigned short* dl = dh + 131072;
        for (int k = t; k < 512; k += 256) {
            unsigned short hi, lo;
            split2(W[k * 256 + hh], hi, lo);
            dh[k] = hi; dl[k] = lo;
        }
    } else {
        int m2 = blk - 1536, mat = m2 >> 8, hh = m2 & 255;
        const float* W;
        if (mat == 6) W = Ws1 + 256 * 256;
        else if (mat == 5) W = Ws1;
        else if (mat & 1) W = W_r2t + ((mat >> 1) + 1) * 512 * 256;
        else W = W_t2r + (mat >> 1) * 512 * 256;
        unsigned short* dh = WT2 + mat * 131072 + hh * 256;
        unsigned short* dl = dh + 65536;
        unsigned short hi, lo;
        split2(W[t * 256 + hh], hi, lo);
        dh[t] = hi; dl[t] = lo;
    }
}

// ---- 2. proj ----
__global__ __launch_bounds__(256) void k_proj(const float* __restrict__ robot_raw,
                                              const float* __restrict__ traw,
                                              const float* __restrict__ Wp,
                                              const float* __restrict__ bp,
                                              const float* __restrict__ Wa0,
                                              float* __restrict__ robot_h,
                                              float* __restrict__ target_h,
                                              float* __restrict__ rWa) {
    int h = threadIdx.x;
    int r0 = blockIdx.x * 2;
    int robot = (r0 < 512);
    const float* in;
    float* out;
    if (robot) { in = robot_raw + r0 * 128; out = robot_h + r0 * 256; }
    else       { in = traw + (r0 - 512) * 128; out = target_h + (r0 - 512) * 256; }
    float a0 = 0, a1 = 0;
    for (int k = 0; k < 128; ++k) {
        float w = Wp[k * 256 + h];
        a0 += in[k] * w; a1 += in[128 + k] * w;
    }
    float b = bp[h];
    a0 += b; a1 += b;
    out[h] = a0; out[256 + h] = a1;

    __shared__ float yl[2][257];
    if (robot) { yl[0][h] = a0; yl[1][h] = a1; }
    __syncthreads();
    if (robot) {
        float c0 = 0, c1 = 0;
        for (int k = 0; k < 256; ++k) {
            float w = Wa0[k * 256 + h];
            c0 += yl[0][k] * w; c1 += yl[1][k] * w;
        }
        rWa[r0 * 256 + h] = c0; rWa[(r0 + 1) * 256 + h] = c1;
    }
}

// ---- 3. update via MFMA split-bf16, 1024 threads / 16 waves ----
__global__ __launch_bounds__(1024) void k_update_mfma(
        float* __restrict__ state, const float* __restrict__ agg,
        const unsigned short* __restrict__ WTm,   // [hi 256x512][lo 256x512]
        const float* __restrict__ bvec, const float* __restrict__ g, const float* __restrict__ be,
        const unsigned short* __restrict__ WT2a,  // [hi 256x256][lo 256x256]
        float* __restrict__ out2a,
        const unsigned short* __restrict__ WT2b, const float* __restrict__ b2b,
        float* __restrict__ out2b) {
    int r0 = blockIdx.x * 16;
    int t = threadIdx.x;
    int w = t >> 6, lane = t & 63;
    int c16 = lane & 15, kg = lane >> 4;
    int col = (w << 4) | c16;

    __shared__ unsigned short Ahi[16 * 512];
    __shared__ unsigned short Alo[16 * 512];
    __shared__ unsigned short Yhi[16 * 256];
    __shared__ unsigned short Ylo[16 * 256];
    __shared__ float red[16][16][2];

    {
        int row = t & 15, kq = t >> 4;   // kq 0..63 -> 8 K-elems each
        const float* src = (kq < 32) ? (state + (r0 + row) * 256 + kq * 8)
                                     : (agg + (r0 + row) * 256 + (kq - 32) * 8);
        float4 a = *(const float4*)(src);
        float4 b2 = *(const float4*)(src + 4);
        unsigned short h[8], lo[8];
        split2(a.x, h[0], lo[0]); split2(a.y, h[1], lo[1]);
        split2(a.z, h[2], lo[2]); split2(a.w, h[3], lo[3]);
        split2(b2.x, h[4], lo[4]); split2(b2.y, h[5], lo[5]);
        split2(b2.z, h[6], lo[6]); split2(b2.w, h[7], lo[7]);
        int byte = row * 1024 + kq * 16;
        byte ^= (row & 7) << 4;
        ushort4* ph = (ushort4*)((char*)Ahi + byte);
        ph[0] = make_ushort4(h[0], h[1], h[2], h[3]);
        ph[1] = make_ushort4(h[4], h[5], h[6], h[7]);
        ushort4* pl = (ushort4*)((char*)Alo + byte);
        pl[0] = make_ushort4(lo[0], lo[1], lo[2], lo[3]);
        pl[1] = make_ushort4(lo[4], lo[5], lo[6], lo[7]);
    }
    __syncthreads();

    f32x4 acc = f32x4{0.f, 0.f, 0.f, 0.f};
    const unsigned short* Bh0 = WTm + col * 512 + kg * 8;
#pragma unroll 4
    for (int ks = 0; ks < 16; ++ks) {
        int ab = c16 * 1024 + ks * 64 + kg * 16;
        ab ^= (c16 & 7) << 4;
        bf16x8 ah = *(const bf16x8*)((const char*)Ahi + ab);
        bf16x8 al = *(const bf16x8*)((const char*)Alo + ab);
        const unsigned short* p = Bh0 + ks * 32;
        bf16x8 bh = *(const bf16x8*)p;
        bf16x8 bl = *(const bf16x8*)(p + 131072);
        acc = __builtin_amdgcn_mfma_f32_16x16x32_bf16(ah, bh, acc, 0, 0, 0);
        acc = __builtin_amdgcn_mfma_f32_16x16x32_bf16(al, bh, acc, 0, 0, 0);
        acc = __builtin_amdgcn_mfma_f32_16x16x32_bf16(ah, bl, acc, 0, 0, 0);
    }

    float x[4];
    {
        float bv = bvec[col];
#pragma unroll
        for (int r = 0; r < 4; ++r) {
            int row = kg * 4 + r;
            x[r] = acc[r] + state[(r0 + row) * 256 + col] + bv;
        }
    }

    float s[4], q[4];
#pragma unroll
    for (int r = 0; r < 4; ++r) {
        s[r] = x[r];
        q[r] = x[r] * x[r];
#pragma unroll
        for (int m = 1; m < 16; m <<= 1) {
            s[r] += __shfl_xor(s[r], m);
            q[r] += __shfl_xor(q[r], m);
        }
    }
    if (c16 == 0) {
#pragma unroll
        for (int r = 0; r < 4; ++r) {
            red[w][kg * 4 + r][0] = s[r];
            red[w][kg * 4 + r][1] = q[r];
        }
    }
    __syncthreads();
    float mr[4], rsr[4];
#pragma unroll
    for (int r = 0; r < 4; ++r) {
        int row = kg * 4 + r;
        float S = 0.f, Q = 0.f;
#pragma unroll
        for (int w2 = 0; w2 < 16; ++w2) { S += red[w2][row][0]; Q += red[w2][row][1]; }
        float m = S * (1.f / 256.f);
        float v = Q * (1.f / 256.f) - m * m;
        mr[r] = m;
        rsr[r] = rsqrtf(v + 1e-5f);
    }

    {
        float gg = g[col], bb = be[col];
#pragma unroll
        for (int r = 0; r < 4; ++r) {
            int row = kg * 4 + r;
            float y = (x[r] - mr[r]) * rsr[r] * gg + bb;
            state[(r0 + row) * 256 + col] = y;
            unsigned short yh, yl2;
            split2(y, yh, yl2);
            int byte = (row * 512 + col * 2) ^ ((row & 7) << 4);
            *(unsigned short*)((char*)Yhi + byte) = yh;
            *(unsigned short*)((char*)Ylo + byte) = yl2;
        }
    }
    __syncthreads();

    f32x4 acc2 = f32x4{0.f, 0.f, 0.f, 0.f};
    f32x4 acc3 = f32x4{0.f, 0.f, 0.f, 0.f};
    const unsigned short* B2h0 = WT2a + col * 256 + kg * 8;
    const unsigned short* B3h0 = WT2b ? (WT2b + col * 256 + kg * 8) : B2h0;
    int haveB = (WT2b != nullptr);
#pragma unroll 4
    for (int ks = 0; ks < 8; ++ks) {
        int ab = c16 * 512 + ks * 64 + kg * 16;
        ab ^= (c16 & 7) << 4;
        bf16x8 ah = *(const bf16x8*)((const char*)Yhi + ab);
        bf16x8 al = *(const bf16x8*)((const char*)Ylo + ab);
        const unsigned short* p = B2h0 + ks * 32;
        bf16x8 bh = *(const bf16x8*)p;
        bf16x8 bl = *(const bf16x8*)(p + 65536);
        acc2 = __builtin_amdgcn_mfma_f32_16x16x32_bf16(ah, bh, acc2, 0, 0, 0);
        acc2 = __builtin_amdgcn_mfma_f32_16x16x32_bf16(al, bh, acc2, 0, 0, 0);
        acc2 = __builtin_amdgcn_mfma_f32_16x16x32_bf16(ah, bl, acc2, 0, 0, 0);
        if (haveB) {
            const unsigned short* p3 = B3h0 + ks * 32;
            bf16x8 bh3 = *(const bf16x8*)p3;
            bf16x8 bl3 = *(const bf16x8*)(p3 + 65536);
            acc3 = __builtin_amdgcn_mfma_f32_16x16x32_bf16(ah, bh3, acc3, 0, 0, 0);
            acc3 = __builtin_amdgcn_mfma_f32_16x16x32_bf16(al, bh3, acc3, 0, 0, 0);
            acc3 = __builtin_amdgcn_mfma_f32_16x16x32_bf16(ah, bl3, acc3, 0, 0, 0);
        }
    }
#pragma unroll
    for (int r = 0; r < 4; ++r) {
        int row = kg * 4 + r;
        out2a[(r0 + row) * 256 + col] = acc2[r];
    }
    if (haveB) {
        float bb2 = b2b[col];
#pragma unroll
        for (int r = 0; r < 4; ++r) {
            int grow = r0 + kg * 4 + r;
            int b0 = grow >> 6, j = grow & 63;
            out2b[(b0 * 256 + col) * 64 + j] = acc3[r] + bb2;
        }
    }
}

// ---- 4. bigpass: 1024 WGs (tile = bid>>1, col-half = bid&1), LDS rowbias ----
__global__ __launch_bounds__(256) void k_bigpass(const unsigned short* __restrict__ edge_bf,
                                                 const unsigned short* __restrict__ WcT,
                                                 const float* __restrict__ bc,
                                                 const float* __restrict__ rowbias,
                                                 float* __restrict__ agg,
                                                 int mode,
                                                 const unsigned short* __restrict__ prefA,
                                                 const unsigned short* __restrict__ prefB,
                                                 int nb) {            // nb = uint4 count of B slice
    int bid = blockIdx.x;
    int tile = bid >> 1, nh = bid & 1;   // tile = b*64 + jj; nh = col half
    int b = tile >> 6, jj = tile & 63;
    int w = threadIdx.x >> 6, lane = threadIdx.x & 63;
    int c16 = lane & 15, kgrp = lane >> 4;

    __shared__ float rbl[64 * 132];      // 64 rows x 128 cols, stride 132 (pad)

    {
        const float* rbsrc = rowbias + (b * 64) * 256 + nh * 128;
#pragma unroll
        for (int k = 0; k < 8; ++k) {
            int f = k * 256 + threadIdx.x;
            int row = f >> 5, c4 = f & 31;
            float4 vv = *(const float4*)(rbsrc + row * 256 + c4 * 4);
            *(float4*)(&rbl[row * 132 + c4 * 4]) = vv;
        }
    }

    int rstride = (mode == 0) ? 8192 : 128;
    const unsigned short* Ap = edge_bf + b * 524288 + ((mode == 0) ? jj * 128 : jj * 8192)
                             + c16 * rstride + 8 * kgrp;
    const unsigned short* Bp = WcT + (nh * 128 + w * 32 + c16) * 128 + 8 * kgrp;

    bf16x8 av[4][4], bv[2][4];
#pragma unroll
    for (int kk = 0; kk < 4; ++kk) {
#pragma unroll
        for (int mi = 0; mi < 4; ++mi)
            av[mi][kk] = *(const bf16x8*)(Ap + mi * 16 * rstride + kk * 32);
#pragma unroll
        for (int ni = 0; ni < 2; ++ni)
            bv[ni][kk] = *(const bf16x8*)(Bp + ni * 2048 + kk * 32);
    }
    __builtin_amdgcn_sched_barrier(0);

    f32x4 acc[4][2];
#pragma unroll
    for (int mi = 0; mi < 4; ++mi)
#pragma unroll
        for (int ni = 0; ni < 2; ++ni) acc[mi][ni] = f32x4{0.f, 0.f, 0.f, 0.f};
#pragma unroll
    for (int kk = 0; kk < 4; ++kk)
#pragma unroll
        for (int mi = 0; mi < 4; ++mi)
#pragma unroll
            for (int ni = 0; ni < 2; ++ni)
                acc[mi][ni] = __builtin_amdgcn_mfma_f32_16x16x32_bf16(av[mi][kk], bv[ni][kk], acc[mi][ni], 0, 0, 0);

    // issue prefetch loads (next update's weights) to overlap epilogue
    int s = (bid >> 4) & 63;
    const uint4* pa = (const uint4*)prefA + (long)s * 512;
    const uint4* pb = (const uint4*)prefB + (long)s * nb;
    uint4 pf0 = pa[threadIdx.x];
    uint4 pf1 = pa[threadIdx.x + 256];
    uint4 pf2 = pb[threadIdx.x];
    uint4 pf3, pf4;
    int big = (nb > 256);
    if (big) { pf3 = pb[threadIdx.x + 256]; pf4 = pb[threadIdx.x + 512]; }
    __builtin_amdgcn_sched_barrier(0);

    __syncthreads();   // rowbias staged

    float colsum[2] = {0.f, 0.f};
#pragma unroll
    for (int ni = 0; ni < 2; ++ni) {
        int colL = w * 32 + ni * 16 + c16;
        float bch = bc[nh * 128 + colL];
#pragma unroll
        for (int mi = 0; mi < 4; ++mi) {
            int rbase = 16 * mi + 4 * kgrp;
#pragma unroll
            for (int r = 0; r < 4; ++r) {
                float v = acc[mi][ni][r] + rbl[(rbase + r) * 132 + colL] + bch;
                colsum[ni] += fmaxf(v, 0.f);
            }
        }
    }
#pragma unroll
    for (int ni = 0; ni < 2; ++ni) {
        colsum[ni] += __shfl_xor(colsum[ni], 16);
        colsum[ni] += __shfl_xor(colsum[ni], 32);
    }
    if (kgrp == 0) {
        float* o = agg + (b * 64 + jj) * 256 + nh * 128 + w * 32 + c16;
#pragma unroll
        for (int ni = 0; ni < 2; ++ni) o[16 * ni] = colsum[ni] * (1.f / 64.f);
    }

    unsigned accp = pf0.x ^ pf0.w ^ pf1.y ^ pf2.z;
    if (big) accp ^= pf3.x ^ pf4.w;
    asm volatile("" :: "v"(accp));
}

// ---- 5. scores: 128 WGs x 256, one output elem per thread ----
__global__ __launch_bounds__(256) void k_scores(const float* __restrict__ rS,
                                                const float* __restrict__ tST,
                                                const float* __restrict__ Ws2,
                                                const float* __restrict__ bs2,
                                                float* __restrict__ scores) {
    int t = blockIdx.x * 256 + threadIdx.x;          // 32768
    int j = t & 63, i = (t >> 6) & 63, b = t >> 12;
    const float* rs = rS + (b * 64 + i) * 256;
    const float* ts = tST + b * 256 * 64 + j;
    float acc = bs2[0];
    for (int h = 0; h < 256; ++h)
        acc += fmaxf(rs[h] + ts[h * 64], 0.f) * Ws2[h];
    scores[t] = acc;
}

// ---- 6. sinkhorn: 8 WGs x 1024, v[4]/thread ----
__global__ __launch_bounds__(1024) void k_sinkhorn(const float* __restrict__ scores,
                                                   float* __restrict__ probs) {
    int b = blockIdx.x;
    int t = threadIdx.x;
    int j = t & 63, rg = t >> 6;
    float v[4];
    const float* src = scores + b * 4096 + rg * 256 + j;
#pragma unroll
    for (int k = 0; k < 4; ++k) v[k] = src[k * 64];

    __shared__ float lm_s[2][16][64];
    __shared__ float ps_s[2][16][64];

    for (int it = 0; it < 10; ++it) {
#pragma unroll
        for (int k = 0; k < 4; ++k) {
            float m = v[k];
#pragma unroll
            for (int s = 1; s < 64; s <<= 1) m = fmaxf(m, __shfl_xor(m, s));
            float e = __expf(v[k] - m), ss = e;
#pragma unroll
            for (int s = 1; s < 64; s <<= 1) ss += __shfl_xor(ss, s);
            v[k] -= m + __logf(ss);
        }
        int p = it & 1;
        float lm = fmaxf(fmaxf(v[0], v[1]), fmaxf(v[2], v[3]));
        float ps = __expf(v[0] - lm) + __expf(v[1] - lm) + __expf(v[2] - lm) + __expf(v[3] - lm);
        lm_s[p][rg][j] = lm; ps_s[p][rg][j] = ps;
        __syncthreads();
        float M = lm_s[p][0][j];
#pragma unroll
        for (int g2 = 1; g2 < 16; ++g2) M = fmaxf(M, lm_s[p][g2][j]);
        float S = 0.f;
#pragma unroll
        for (int g2 = 0; g2 < 16; ++g2) S += ps_s[p][g2][j] * __expf(lm_s[p][g2][j] - M);
        float lse = M + __logf(S);
#pragma unroll
        for (int k = 0; k < 4; ++k) v[k] -= lse;
    }
    float* dst = probs + b * 4096 + rg * 256 + j;
#pragma unroll
    for (int k = 0; k < 4; ++k) dst[k * 64] = __expf(v[k]);
}

extern "C" void kernel_launch(void* const* d_in, const int* in_sizes, int n_in,
                              void* d_out, int out_size, void* d_ws, size_t ws_size,
                              hipStream_t stream) {
    const float* robot_raw = (const float*)d_in[0];
    const float* edge_raw  = (const float*)d_in[1];
    const float* Wp    = (const float*)d_in[2];
    const float* bp    = (const float*)d_in[3];
    const float* W_r2t = (const float*)d_in[4];
    const float* b_r2t = (const float*)d_in[5];
    const float* W_pt  = (const float*)d_in[6];
    const float* b_pt  = (const float*)d_in[7];
    const float* g_t   = (const float*)d_in[8];
    const float* be_t  = (const float*)d_in[9];
    const float* W_t2r = (const float*)d_in[10];
    const float* b_t2r = (const float*)d_in[11];
    const float* W_pr  = (const float*)d_in[12];
    const float* b_pr  = (const float*)d_in[13];
    const float* g_r   = (const float*)d_in[14];
    const float* be_r  = (const float*)d_in[15];
    const float* Ws1   = (const float*)d_in[16];
    const float* bs1   = (const float*)d_in[17];
    const float* Ws2   = (const float*)d_in[18];
    const float* bs2   = (const float*)d_in[19];

    char* ws = (char*)d_ws;
    unsigned short* edge_bf = (unsigned short*)(ws);            // 8,388,608
    float* traw     = (float*)(ws + 8388608);                   //   262,144
    float* robot_h  = (float*)(ws + 8650752);                   //   524,288
    float* target_h = (float*)(ws + 9175040);                   //   524,288
    unsigned short* WcT = (unsigned short*)(ws + 9699328);      //   393,216
    float* bc       = (float*)(ws + 10092544);                  //     6,144
    float* rWa      = (float*)(ws + 10098688);                  //   524,288
    float* tWa      = (float*)(ws + 10622976);                  //   524,288
    float* agg      = (float*)(ws + 11147264);                  //   524,288
    float* rS       = (float*)(ws + 11671552);                  //   524,288
    float* tST      = (float*)(ws + 12195840);                  //   524,288
    unsigned short* WTbig = (unsigned short*)(ws + 12720128);   // 3,145,728
    unsigned short* WT2   = (unsigned short*)(ws + 15865856);   // 1,835,008

    float* out    = (float*)d_out;
    float* probs  = out;            // output 0
    float* scores = out + 32768;    // output 1

    hipLaunchKernelGGL(k_prep_w, dim3(4614), dim3(256), 0, stream,
                       edge_raw, edge_bf, traw,
                       Wp, bp, W_r2t, b_r2t, W_t2r, b_t2r, W_pt, W_pr, Ws1, WcT, bc, WTbig, WT2);
    hipLaunchKernelGGL(k_proj, dim3(512), dim3(256), 0, stream,
                       robot_raw, traw, Wp, bp, W_r2t, robot_h, target_h, rWa);

    for (int l = 0; l < 3; ++l) {
        // r2t bigpass + prefetch of the target-update weights
        {
            const unsigned short* pA = WTbig + (2 * l) * 262144;
            const unsigned short* pB = WT2 + (2 * l) * 131072;
            int nb = (l == 2) ? 768 : 256;                     // l==2 covers mats 4..6
            hipLaunchKernelGGL(k_bigpass, dim3(1024), dim3(256), 0, stream,
                               edge_bf, WcT + (2 * l) * 32768, bc + (2 * l) * 256, rWa, agg, 0,
                               pA, pB, nb);
        }
        const unsigned short* W2b = (l == 2) ? (WT2 + 6 * 131072) : nullptr;
        const float* b2b = (l == 2) ? bs1 : nullptr;
        float* o2b = (l == 2) ? tST : nullptr;
        hipLaunchKernelGGL(k_update_mfma, dim3(32), dim3(1024), 0, stream,
                           target_h, agg, WTbig + (2 * l) * 262144,
                           b_pt + l * 256, g_t + l * 256, be_t + l * 256,
                           WT2 + (2 * l) * 131072, tWa, W2b, b2b, o2b);
        // t2r bigpass + prefetch of the robot-update weights
        {
            const unsigned short* pA = WTbig + (2 * l + 1) * 262144;
            int m2 = (l < 2) ? (2 * l + 1) : 5;
            const unsigned short* pB = WT2 + m2 * 131072;
            hipLaunchKernelGGL(k_bigpass, dim3(1024), dim3(256), 0, stream,
                               edge_bf, WcT + (2 * l + 1) * 32768, bc + (2 * l + 1) * 256, tWa, agg, 1,
                               pA, pB, 256);
        }
        const unsigned short* W2a = (l < 2) ? (WT2 + (2 * l + 1) * 131072) : (WT2 + 5 * 131072);
        float* o2a = (l < 2) ? rWa : rS;
        hipLaunchKernelGGL(k_update_mfma, dim3(32), dim3(1024), 0, stream,
                           robot_h, agg, WTbig + (2 * l + 1) * 262144,
                           b_pr + l * 256, g_r + l * 256, be_r + l * 256,
                           W2a, o2a, (const unsigned short*)nullptr, (const float*)nullptr, (float*)nullptr);
    }

    hipLaunchKernelGGL(k_scores, dim3(128), dim3(256), 0, stream, rS, tST, Ws2, bs2, scores);
    hipLaunchKernelGGL(k_sinkhorn, dim3(8), dim3(1024), 0, stream, scores, probs);
}

// Round 11
// 321.805 us; speedup vs baseline: 2.2829x; 1.0642x over previous
//
#include <hip/hip_runtime.h>

// NavAssignNet on MI355X — round 11: exact revert to round 7 (measured best,
// 321us). Round 9/10's 1024-WG bigpass doubled A-fragment VMEM traffic
// (each edge tile loaded by 2 WGs) for an epilogue that wasn't the
// bottleneck -> +21us. This run is the confirming A/B.

typedef short bf16x8 __attribute__((ext_vector_type(8)));
typedef float f32x4 __attribute__((ext_vector_type(4)));

#define DEV static __device__ __forceinline__

DEV unsigned short f2bf(float x) {
    unsigned u = __float_as_uint(x);
    return (unsigned short)((u + 0x7fffu + ((u >> 16) & 1u)) >> 16);
}
DEV void split2(float v, unsigned short& hi, unsigned short& lo) {
    unsigned short h = f2bf(v);
    float fh = __uint_as_float(((unsigned)h) << 16);
    hi = h;
    lo = f2bf(v - fh);
}

// ---- 1. prep+weights merged ----
__global__ __launch_bounds__(256) void k_prep_w(const float* __restrict__ edge,
                                                unsigned short* __restrict__ edge_bf,
                                                float* __restrict__ traw,
                                                const float* __restrict__ Wp,
                                                const float* __restrict__ bp,
                                                const float* __restrict__ W_r2t,
                                                const float* __restrict__ b_r2t,
                                                const float* __restrict__ W_t2r,
                                                const float* __restrict__ b_t2r,
                                                const float* __restrict__ W_pt,
                                                const float* __restrict__ W_pr,
                                                const float* __restrict__ Ws1,
                                                unsigned short* __restrict__ WcT,
                                                float* __restrict__ bc,
                                                unsigned short* __restrict__ WTbig,
                                                unsigned short* __restrict__ WT2) {
    if (blockIdx.x < 512) {
        int wg = blockIdx.x;             // b*64 + j
        int b = wg >> 6, j = wg & 63;
        int t = threadIdx.x;
        int d = t & 127, ih = t >> 7;
        float s = 0.f;
        long base = ((long)(b * 64 + ih * 32) * 64 + j) * 128 + d;
#pragma unroll 8
        for (int ii = 0; ii < 32; ++ii) {
            long idx = base + (long)ii * 8192;
            float v = edge[idx];
            s += v;
            edge_bf[idx] = f2bf(v);
        }
        __shared__ float part[128];
        if (ih == 1) part[d] = s;
        __syncthreads();
        if (ih == 0) traw[(b * 64 + j) * 128 + d] = (s + part[d]) * (1.f / 64.f);
        return;
    }
    int blk0 = blockIdx.x - 512;
    int h = threadIdx.x;
    if (blk0 < 774) {
        int blk = blk0;
        if (blk < 768) {
            int p = blk >> 7, d = blk & 127, l = p >> 1;
            const float* Wb = ((p & 1) ? W_t2r : W_r2t) + l * 512 * 256 + 256 * 256;
            float acc = 0.f;
            for (int k = 0; k < 256; ++k) acc += Wp[d * 256 + k] * Wb[k * 256 + h];
            WcT[p * 32768 + h * 128 + d] = f2bf(acc);
        } else {
            int p = blk - 768, l = p >> 1;
            const float* Wb = ((p & 1) ? W_t2r : W_r2t) + l * 512 * 256 + 256 * 256;
            const float* bm = ((p & 1) ? b_t2r : b_r2t) + l * 256;
            float acc = bm[h];
            for (int k = 0; k < 256; ++k) acc += bp[k] * Wb[k * 256 + h];
            bc[p * 256 + h] = acc;
        }
        return;
    }
    int blk = blk0 - 774, t = threadIdx.x;
    if (blk < 1536) {
        int mat = blk >> 8, hh = blk & 255, l = mat >> 1;
        const float* W = ((mat & 1) ? W_pr : W_pt) + l * 512 * 256;
        unsigned short* dh = WTbig + mat * 262144 + hh * 512;
        unsigned short* dl = dh + 131072;
        for (int k = t; k < 512; k += 256) {
            unsigned short hi, lo;
            split2(W[k * 256 + hh], hi, lo);
            dh[k] = hi; dl[k] = lo;
        }
    } else {
        int m2 = blk - 1536, mat = m2 >> 8, hh = m2 & 255;
        const float* W;
        if (mat == 6) W = Ws1 + 256 * 256;
        else if (mat == 5) W = Ws1;
        else if (mat & 1) W = W_r2t + ((mat >> 1) + 1) * 512 * 256;
        else W = W_t2r + (mat >> 1) * 512 * 256;
        unsigned short* dh = WT2 + mat * 131072 + hh * 256;
        unsigned short* dl = dh + 65536;
        unsigned short hi, lo;
        split2(W[t * 256 + hh], hi, lo);
        dh[t] = hi; dl[t] = lo;
    }
}

// ---- 2. proj: robot_h/target_h = X @ Wp + bp ; robot WGs also emit rWa0 ----
__global__ __launch_bounds__(256) void k_proj(const float* __restrict__ robot_raw,
                                              const float* __restrict__ traw,
                                              const float* __restrict__ Wp,
                                              const float* __restrict__ bp,
                                              const float* __restrict__ Wa0,
                                              float* __restrict__ robot_h,
                                              float* __restrict__ target_h,
                                              float* __restrict__ rWa) {
    int h = threadIdx.x;
    int r0 = blockIdx.x * 2;
    int robot = (r0 < 512);
    const float* in;
    float* out;
    if (robot) { in = robot_raw + r0 * 128; out = robot_h + r0 * 256; }
    else       { in = traw + (r0 - 512) * 128; out = target_h + (r0 - 512) * 256; }
    float a0 = 0, a1 = 0;
    for (int k = 0; k < 128; ++k) {
        float w = Wp[k * 256 + h];
        a0 += in[k] * w; a1 += in[128 + k] * w;
    }
    float b = bp[h];
    a0 += b; a1 += b;
    out[h] = a0; out[256 + h] = a1;

    __shared__ float yl[2][257];
    if (robot) { yl[0][h] = a0; yl[1][h] = a1; }
    __syncthreads();
    if (robot) {
        float c0 = 0, c1 = 0;
        for (int k = 0; k < 256; ++k) {
            float w = Wa0[k * 256 + h];
            c0 += yl[0][k] * w; c1 += yl[1][k] * w;
        }
        rWa[r0 * 256 + h] = c0; rWa[(r0 + 1) * 256 + h] = c1;
    }
}

// ---- 3. update via MFMA split-bf16, 1024 threads / 16 waves (16 cols each) ----
__global__ __launch_bounds__(1024) void k_update_mfma(
        float* __restrict__ state, const float* __restrict__ agg,
        const unsigned short* __restrict__ WTm,   // [hi 256x512][lo 256x512]
        const float* __restrict__ bvec, const float* __restrict__ g, const float* __restrict__ be,
        const unsigned short* __restrict__ WT2a,  // [hi 256x256][lo 256x256]
        float* __restrict__ out2a,
        const unsigned short* __restrict__ WT2b, const float* __restrict__ b2b,
        float* __restrict__ out2b) {
    int r0 = blockIdx.x * 16;
    int t = threadIdx.x;
    int w = t >> 6, lane = t & 63;
    int c16 = lane & 15, kg = lane >> 4;
    int col = (w << 4) | c16;

    __shared__ unsigned short Ahi[16 * 512];
    __shared__ unsigned short Alo[16 * 512];
    __shared__ unsigned short Yhi[16 * 256];
    __shared__ unsigned short Ylo[16 * 256];
    __shared__ float red[16][16][2];

    // stage A = [state | agg] rows r0..r0+15 as swizzled hi/lo bf16 (8 elems/thread)
    {
        int row = t & 15, kq = t >> 4;   // kq 0..63 -> 8 K-elems each
        const float* src = (kq < 32) ? (state + (r0 + row) * 256 + kq * 8)
                                     : (agg + (r0 + row) * 256 + (kq - 32) * 8);
        float4 a = *(const float4*)(src);
        float4 b2 = *(const float4*)(src + 4);
        unsigned short h[8], lo[8];
        split2(a.x, h[0], lo[0]); split2(a.y, h[1], lo[1]);
        split2(a.z, h[2], lo[2]); split2(a.w, h[3], lo[3]);
        split2(b2.x, h[4], lo[4]); split2(b2.y, h[5], lo[5]);
        split2(b2.z, h[6], lo[6]); split2(b2.w, h[7], lo[7]);
        int byte = row * 1024 + kq * 16;
        byte ^= (row & 7) << 4;
        ushort4* ph = (ushort4*)((char*)Ahi + byte);
        ph[0] = make_ushort4(h[0], h[1], h[2], h[3]);
        ph[1] = make_ushort4(h[4], h[5], h[6], h[7]);
        ushort4* pl = (ushort4*)((char*)Alo + byte);
        pl[0] = make_ushort4(lo[0], lo[1], lo[2], lo[3]);
        pl[1] = make_ushort4(lo[4], lo[5], lo[6], lo[7]);
    }
    __syncthreads();

    // main GEMM: K=512, 3-term split, 1 col-tile per wave
    f32x4 acc = f32x4{0.f, 0.f, 0.f, 0.f};
    const unsigned short* Bh0 = WTm + col * 512 + kg * 8;
#pragma unroll 4
    for (int ks = 0; ks < 16; ++ks) {
        int ab = c16 * 1024 + ks * 64 + kg * 16;
        ab ^= (c16 & 7) << 4;
        bf16x8 ah = *(const bf16x8*)((const char*)Ahi + ab);
        bf16x8 al = *(const bf16x8*)((const char*)Alo + ab);
        const unsigned short* p = Bh0 + ks * 32;
        bf16x8 bh = *(const bf16x8*)p;
        bf16x8 bl = *(const bf16x8*)(p + 131072);
        acc = __builtin_amdgcn_mfma_f32_16x16x32_bf16(ah, bh, acc, 0, 0, 0);
        acc = __builtin_amdgcn_mfma_f32_16x16x32_bf16(al, bh, acc, 0, 0, 0);
        acc = __builtin_amdgcn_mfma_f32_16x16x32_bf16(ah, bl, acc, 0, 0, 0);
    }

    // residual + bias
    float x[4];
    {
        float bv = bvec[col];
#pragma unroll
        for (int r = 0; r < 4; ++r) {
            int row = kg * 4 + r;
            x[r] = acc[r] + state[(r0 + row) * 256 + col] + bv;
        }
    }

    // LN stats: reduce over 16 cols in-wave, then 16 waves via LDS
    float s[4], q[4];
#pragma unroll
    for (int r = 0; r < 4; ++r) {
        s[r] = x[r];
        q[r] = x[r] * x[r];
#pragma unroll
        for (int m = 1; m < 16; m <<= 1) {
            s[r] += __shfl_xor(s[r], m);
            q[r] += __shfl_xor(q[r], m);
        }
    }
    if (c16 == 0) {
#pragma unroll
        for (int r = 0; r < 4; ++r) {
            red[w][kg * 4 + r][0] = s[r];
            red[w][kg * 4 + r][1] = q[r];
        }
    }
    __syncthreads();
    float mr[4], rsr[4];
#pragma unroll
    for (int r = 0; r < 4; ++r) {
        int row = kg * 4 + r;
        float S = 0.f, Q = 0.f;
#pragma unroll
        for (int w2 = 0; w2 < 16; ++w2) { S += red[w2][row][0]; Q += red[w2][row][1]; }
        float m = S * (1.f / 256.f);
        float v = Q * (1.f / 256.f) - m * m;
        mr[r] = m;
        rsr[r] = rsqrtf(v + 1e-5f);
    }

    // y = LN(x): store to state + stage bf16 hi/lo into LDS (swizzled)
    {
        float gg = g[col], bb = be[col];
#pragma unroll
        for (int r = 0; r < 4; ++r) {
            int row = kg * 4 + r;
            float y = (x[r] - mr[r]) * rsr[r] * gg + bb;
            state[(r0 + row) * 256 + col] = y;
            unsigned short yh, yl2;
            split2(y, yh, yl2);
            int byte = (row * 512 + col * 2) ^ ((row & 7) << 4);
            *(unsigned short*)((char*)Yhi + byte) = yh;
            *(unsigned short*)((char*)Ylo + byte) = yl2;
        }
    }
    __syncthreads();

    // fused GEMM(s): y @ W2a (-> out2a), optional y @ W2b + b2b (-> out2b transposed)
    f32x4 acc2 = f32x4{0.f, 0.f, 0.f, 0.f};
    f32x4 acc3 = f32x4{0.f, 0.f, 0.f, 0.f};
    const unsigned short* B2h0 = WT2a + col * 256 + kg * 8;
    const unsigned short* B3h0 = WT2b ? (WT2b + col * 256 + kg * 8) : B2h0;
    int haveB = (WT2b != nullptr);
#pragma unroll 4
    for (int ks = 0; ks < 8; ++ks) {
        int ab = c16 * 512 + ks * 64 + kg * 16;
        ab ^= (c16 & 7) << 4;
        bf16x8 ah = *(const bf16x8*)((const char*)Yhi + ab);
        bf16x8 al = *(const bf16x8*)((const char*)Ylo + ab);
        const unsigned short* p = B2h0 + ks * 32;
        bf16x8 bh = *(const bf16x8*)p;
        bf16x8 bl = *(const bf16x8*)(p + 65536);
        acc2 = __builtin_amdgcn_mfma_f32_16x16x32_bf16(ah, bh, acc2, 0, 0, 0);
        acc2 = __builtin_amdgcn_mfma_f32_16x16x32_bf16(al, bh, acc2, 0, 0, 0);
        acc2 = __builtin_amdgcn_mfma_f32_16x16x32_bf16(ah, bl, acc2, 0, 0, 0);
        if (haveB) {
            const unsigned short* p3 = B3h0 + ks * 32;
            bf16x8 bh3 = *(const bf16x8*)p3;
            bf16x8 bl3 = *(const bf16x8*)(p3 + 65536);
            acc3 = __builtin_amdgcn_mfma_f32_16x16x32_bf16(ah, bh3, acc3, 0, 0, 0);
            acc3 = __builtin_amdgcn_mfma_f32_16x16x32_bf16(al, bh3, acc3, 0, 0, 0);
            acc3 = __builtin_amdgcn_mfma_f32_16x16x32_bf16(ah, bl3, acc3, 0, 0, 0);
        }
    }
#pragma unroll
    for (int r = 0; r < 4; ++r) {
        int row = kg * 4 + r;
        out2a[(r0 + row) * 256 + col] = acc2[r];
    }
    if (haveB) {
        float bb2 = b2b[col];
#pragma unroll
        for (int r = 0; r < 4; ++r) {
            int grow = r0 + kg * 4 + r;
            int b0 = grow >> 6, j = grow & 63;
            out2b[(b0 * 256 + col) * 64 + j] = acc3[r] + bb2;
        }
    }
}

// ---- 4. bigpass: hoisted loads; prefetch issued mid-kernel, consumed at end ----
__global__ __launch_bounds__(256) void k_bigpass(const unsigned short* __restrict__ edge_bf,
                                                 const unsigned short* __restrict__ WcT,
                                                 const float* __restrict__ bc,
                                                 const float* __restrict__ rowbias,
                                                 float* __restrict__ agg,
                                                 int mode,
                                                 const unsigned short* __restrict__ prefA,
                                                 const unsigned short* __restrict__ prefB,
                                                 int nb) {            // nb = uint4 count of B slice
    int wg = blockIdx.x;                 // 512 = b*64 + jj
    int b = wg >> 6, jj = wg & 63;
    int w = threadIdx.x >> 6, lane = threadIdx.x & 63;
    int row16 = lane & 15, kgrp = lane >> 4;

    int rstride = (mode == 0) ? 8192 : 128;
    const unsigned short* Ap = edge_bf + b * 524288 + ((mode == 0) ? jj * 128 : jj * 8192)
                             + row16 * rstride + 8 * kgrp;
    const unsigned short* Bp = WcT + (64 * w + row16) * 128 + 8 * kgrp;

    // hoist ALL fragment loads: one latency window
    bf16x8 av[4][4], bv[4][4];
#pragma unroll
    for (int kk = 0; kk < 4; ++kk) {
#pragma unroll
        for (int mi = 0; mi < 4; ++mi)
            av[mi][kk] = *(const bf16x8*)(Ap + mi * 16 * rstride + kk * 32);
#pragma unroll
        for (int ni = 0; ni < 4; ++ni)
            bv[ni][kk] = *(const bf16x8*)(Bp + ni * 2048 + kk * 32);
    }
    __builtin_amdgcn_sched_barrier(0);

    f32x4 acc[4][4];
#pragma unroll
    for (int mi = 0; mi < 4; ++mi)
#pragma unroll
        for (int ni = 0; ni < 4; ++ni) acc[mi][ni] = f32x4{0.f, 0.f, 0.f, 0.f};
#pragma unroll
    for (int kk = 0; kk < 4; ++kk)
#pragma unroll
        for (int mi = 0; mi < 4; ++mi)
#pragma unroll
            for (int ni = 0; ni < 4; ++ni)
                acc[mi][ni] = __builtin_amdgcn_mfma_f32_16x16x32_bf16(av[mi][kk], bv[ni][kk], acc[mi][ni], 0, 0, 0);

    // issue prefetch loads now (next update's weight panels, 1/64 slice);
    // their latency overlaps the epilogue, consumed at kernel end.
    int s = (blockIdx.x >> 3) & 63;
    const uint4* pa = (const uint4*)prefA + (long)s * 512;   // A slice = 512 uint4
    const uint4* pb = (const uint4*)prefB + (long)s * nb;
    uint4 pf0 = pa[threadIdx.x];
    uint4 pf1 = pa[threadIdx.x + 256];
    uint4 pf2 = pb[threadIdx.x];
    uint4 pf3, pf4;
    int big = (nb > 256);
    if (big) { pf3 = pb[threadIdx.x + 256]; pf4 = pb[threadIdx.x + 512]; }
    __builtin_amdgcn_sched_barrier(0);

    const float* rb = rowbias + (b * 64) * 256;
    float colsum[4] = {0.f, 0.f, 0.f, 0.f};
#pragma unroll
    for (int ni = 0; ni < 4; ++ni) {
        int col = 64 * w + 16 * ni + row16;
        float bch = bc[col];
#pragma unroll
        for (int mi = 0; mi < 4; ++mi) {
            int rbase = 16 * mi + 4 * kgrp;
#pragma unroll
            for (int r = 0; r < 4; ++r) {
                float v = acc[mi][ni][r] + rb[(rbase + r) * 256 + col] + bch;
                colsum[ni] += fmaxf(v, 0.f);
            }
        }
    }
#pragma unroll
    for (int ni = 0; ni < 4; ++ni) {
        colsum[ni] += __shfl_xor(colsum[ni], 16);
        colsum[ni] += __shfl_xor(colsum[ni], 32);
    }
    if (kgrp == 0) {
        float* o = agg + (b * 64 + jj) * 256 + 64 * w + row16;
#pragma unroll
        for (int ni = 0; ni < 4; ++ni) o[16 * ni] = colsum[ni] * (1.f / 64.f);
    }

    unsigned accp = pf0.x ^ pf0.w ^ pf1.y ^ pf2.z;
    if (big) accp ^= pf3.x ^ pf4.w;
    asm volatile("" :: "v"(accp));
}

// ---- 5. scores ----
__global__ __launch_bounds__(256) void k_scores(const float* __restrict__ rS,
                                                const float* __restrict__ tST,
                                                const float* __restrict__ Ws2,
                                                const float* __restrict__ bs2,
                                                float* __restrict__ scores) {
    int t = blockIdx.x * 256 + threadIdx.x;          // 32768
    int j = t & 63, i = (t >> 6) & 63, b = t >> 12;
    const float* rs = rS + (b * 64 + i) * 256;
    const float* ts = tST + b * 256 * 64 + j;
    float acc = bs2[0];
    for (int h = 0; h < 256; ++h)
        acc += fmaxf(rs[h] + ts[h * 64], 0.f) * Ws2[h];
    scores[t] = acc;
}

// ---- 6. sinkhorn: 1024 threads, v[4]/thread ----
__global__ __launch_bounds__(1024) void k_sinkhorn(const float* __restrict__ scores,
                                                   float* __restrict__ probs) {
    int b = blockIdx.x;
    int t = threadIdx.x;
    int j = t & 63, rg = t >> 6;         // 16 row-groups x 4 rows
    float v[4];
    const float* src = scores + b * 4096 + rg * 256 + j;
#pragma unroll
    for (int k = 0; k < 4; ++k) v[k] = src[k * 64];

    __shared__ float lm_s[2][16][64];
    __shared__ float ps_s[2][16][64];

    for (int it = 0; it < 10; ++it) {
#pragma unroll
        for (int k = 0; k < 4; ++k) {
            float m = v[k];
#pragma unroll
            for (int s = 1; s < 64; s <<= 1) m = fmaxf(m, __shfl_xor(m, s));
            float e = __expf(v[k] - m), ss = e;
#pragma unroll
            for (int s = 1; s < 64; s <<= 1) ss += __shfl_xor(ss, s);
            v[k] -= m + __logf(ss);
        }
        int p = it & 1;
        float lm = fmaxf(fmaxf(v[0], v[1]), fmaxf(v[2], v[3]));
        float ps = __expf(v[0] - lm) + __expf(v[1] - lm) + __expf(v[2] - lm) + __expf(v[3] - lm);
        lm_s[p][rg][j] = lm; ps_s[p][rg][j] = ps;
        __syncthreads();
        float M = lm_s[p][0][j];
#pragma unroll
        for (int g2 = 1; g2 < 16; ++g2) M = fmaxf(M, lm_s[p][g2][j]);
        float S = 0.f;
#pragma unroll
        for (int g2 = 0; g2 < 16; ++g2) S += ps_s[p][g2][j] * __expf(lm_s[p][g2][j] - M);
        float lse = M + __logf(S);
#pragma unroll
        for (int k = 0; k < 4; ++k) v[k] -= lse;
    }
    float* dst = probs + b * 4096 + rg * 256 + j;
#pragma unroll
    for (int k = 0; k < 4; ++k) dst[k * 64] = __expf(v[k]);
}

extern "C" void kernel_launch(void* const* d_in, const int* in_sizes, int n_in,
                              void* d_out, int out_size, void* d_ws, size_t ws_size,
                              hipStream_t stream) {
    const float* robot_raw = (const float*)d_in[0];
    const float* edge_raw  = (const float*)d_in[1];
    const float* Wp    = (const float*)d_in[2];
    const float* bp    = (const float*)d_in[3];
    const float* W_r2t = (const float*)d_in[4];
    const float* b_r2t = (const float*)d_in[5];
    const float* W_pt  = (const float*)d_in[6];
    const float* b_pt  = (const float*)d_in[7];
    const float* g_t   = (const float*)d_in[8];
    const float* be_t  = (const float*)d_in[9];
    const float* W_t2r = (const float*)d_in[10];
    const float* b_t2r = (const float*)d_in[11];
    const float* W_pr  = (const float*)d_in[12];
    const float* b_pr  = (const float*)d_in[13];
    const float* g_r   = (const float*)d_in[14];
    const float* be_r  = (const float*)d_in[15];
    const float* Ws1   = (const float*)d_in[16];
    const float* bs1   = (const float*)d_in[17];
    const float* Ws2   = (const float*)d_in[18];
    const float* bs2   = (const float*)d_in[19];

    char* ws = (char*)d_ws;
    unsigned short* edge_bf = (unsigned short*)(ws);            // 8,388,608
    float* traw     = (float*)(ws + 8388608);                   //   262,144
    float* robot_h  = (float*)(ws + 8650752);                   //   524,288
    float* target_h = (float*)(ws + 9175040);                   //   524,288
    unsigned short* WcT = (unsigned short*)(ws + 9699328);      //   393,216
    float* bc       = (float*)(ws + 10092544);                  //     6,144
    float* rWa      = (float*)(ws + 10098688);                  //   524,288
    float* tWa      = (float*)(ws + 10622976);                  //   524,288
    float* agg      = (float*)(ws + 11147264);                  //   524,288
    float* rS       = (float*)(ws + 11671552);                  //   524,288
    float* tST      = (float*)(ws + 12195840);                  //   524,288
    unsigned short* WTbig = (unsigned short*)(ws + 12720128);   // 3,145,728
    unsigned short* WT2   = (unsigned short*)(ws + 15865856);   // 1,835,008

    float* out    = (float*)d_out;
    float* probs  = out;            // output 0
    float* scores = out + 32768;    // output 1

    hipLaunchKernelGGL(k_prep_w, dim3(4614), dim3(256), 0, stream,
                       edge_raw, edge_bf, traw,
                       Wp, bp, W_r2t, b_r2t, W_t2r, b_t2r, W_pt, W_pr, Ws1, WcT, bc, WTbig, WT2);
    hipLaunchKernelGGL(k_proj, dim3(512), dim3(256), 0, stream,
                       robot_raw, traw, Wp, bp, W_r2t, robot_h, target_h, rWa);

    for (int l = 0; l < 3; ++l) {
        // r2t bigpass + prefetch of the target-update weights
        {
            const unsigned short* pA = WTbig + (2 * l) * 262144;
            const unsigned short* pB = WT2 + (2 * l) * 131072;
            int nb = (l == 2) ? 768 : 256;                     // l==2 covers mats 4..6
            hipLaunchKernelGGL(k_bigpass, dim3(512), dim3(256), 0, stream,
                               edge_bf, WcT + (2 * l) * 32768, bc + (2 * l) * 256, rWa, agg, 0,
                               pA, pB, nb);
        }
        const unsigned short* W2b = (l == 2) ? (WT2 + 6 * 131072) : nullptr;
        const float* b2b = (l == 2) ? bs1 : nullptr;
        float* o2b = (l == 2) ? tST : nullptr;
        hipLaunchKernelGGL(k_update_mfma, dim3(32), dim3(1024), 0, stream,
                           target_h, agg, WTbig + (2 * l) * 262144,
                           b_pt + l * 256, g_t + l * 256, be_t + l * 256,
                           WT2 + (2 * l) * 131072, tWa, W2b, b2b, o2b);
        // t2r bigpass + prefetch of the robot-update weights
        {
            const unsigned short* pA = WTbig + (2 * l + 1) * 262144;
            int m2 = (l < 2) ? (2 * l + 1) : 5;
            const unsigned short* pB = WT2 + m2 * 131072;
            hipLaunchKernelGGL(k_bigpass, dim3(512), dim3(256), 0, stream,
                               edge_bf, WcT + (2 * l + 1) * 32768, bc + (2 * l + 1) * 256, tWa, agg, 1,
                               pA, pB, 256);
        }
        const unsigned short* W2a = (l < 2) ? (WT2 + (2 * l + 1) * 131072) : (WT2 + 5 * 131072);
        float* o2a = (l < 2) ? rWa : rS;
        hipLaunchKernelGGL(k_update_mfma, dim3(32), dim3(1024), 0, stream,
                           robot_h, agg, WTbig + (2 * l + 1) * 262144,
                           b_pr + l * 256, g_r + l * 256, be_r + l * 256,
                           W2a, o2a, (const unsigned short*)nullptr, (const float*)nullptr, (float*)nullptr);
    }

    hipLaunchKernelGGL(k_scores, dim3(128), dim3(256), 0, stream, rS, tST, Ws2, bs2, scores);
    hipLaunchKernelGGL(k_sinkhorn, dim3(8), dim3(1024), 0, stream, scores, probs);
}

// Round 12
// 281.824 us; speedup vs baseline: 2.6067x; 1.1419x over previous
//
#include <hip/hip_runtime.h>

// NavAssignNet on MI355X — round 12: R7/R11 baseline + update main-GEMM uses
// 2-term split (ah*bh + al*bh: A bf16x2, B plain bf16). Halves the update's
// weight stream (512->256KB/WG), 48->32 MFMA; GEMM2 keeps 3-term. WTbig lo
// planes no longer written/prefetched. Predicted absmax ~1e-2 (thr 3.8e-2).

typedef short bf16x8 __attribute__((ext_vector_type(8)));
typedef float f32x4 __attribute__((ext_vector_type(4)));

#define DEV static __device__ __forceinline__

DEV unsigned short f2bf(float x) {
    unsigned u = __float_as_uint(x);
    return (unsigned short)((u + 0x7fffu + ((u >> 16) & 1u)) >> 16);
}
DEV void split2(float v, unsigned short& hi, unsigned short& lo) {
    unsigned short h = f2bf(v);
    float fh = __uint_as_float(((unsigned)h) << 16);
    hi = h;
    lo = f2bf(v - fh);
}

// ---- 1. prep+weights merged ----
__global__ __launch_bounds__(256) void k_prep_w(const float* __restrict__ edge,
                                                unsigned short* __restrict__ edge_bf,
                                                float* __restrict__ traw,
                                                const float* __restrict__ Wp,
                                                const float* __restrict__ bp,
                                                const float* __restrict__ W_r2t,
                                                const float* __restrict__ b_r2t,
                                                const float* __restrict__ W_t2r,
                                                const float* __restrict__ b_t2r,
                                                const float* __restrict__ W_pt,
                                                const float* __restrict__ W_pr,
                                                const float* __restrict__ Ws1,
                                                unsigned short* __restrict__ WcT,
                                                float* __restrict__ bc,
                                                unsigned short* __restrict__ WTbig,
                                                unsigned short* __restrict__ WT2) {
    if (blockIdx.x < 512) {
        int wg = blockIdx.x;             // b*64 + j
        int b = wg >> 6, j = wg & 63;
        int t = threadIdx.x;
        int d = t & 127, ih = t >> 7;
        float s = 0.f;
        long base = ((long)(b * 64 + ih * 32) * 64 + j) * 128 + d;
#pragma unroll 8
        for (int ii = 0; ii < 32; ++ii) {
            long idx = base + (long)ii * 8192;
            float v = edge[idx];
            s += v;
            edge_bf[idx] = f2bf(v);
        }
        __shared__ float part[128];
        if (ih == 1) part[d] = s;
        __syncthreads();
        if (ih == 0) traw[(b * 64 + j) * 128 + d] = (s + part[d]) * (1.f / 64.f);
        return;
    }
    int blk0 = blockIdx.x - 512;
    int h = threadIdx.x;
    if (blk0 < 774) {
        int blk = blk0;
        if (blk < 768) {
            int p = blk >> 7, d = blk & 127, l = p >> 1;
            const float* Wb = ((p & 1) ? W_t2r : W_r2t) + l * 512 * 256 + 256 * 256;
            float acc = 0.f;
            for (int k = 0; k < 256; ++k) acc += Wp[d * 256 + k] * Wb[k * 256 + h];
            WcT[p * 32768 + h * 128 + d] = f2bf(acc);
        } else {
            int p = blk - 768, l = p >> 1;
            const float* Wb = ((p & 1) ? W_t2r : W_r2t) + l * 512 * 256 + 256 * 256;
            const float* bm = ((p & 1) ? b_t2r : b_r2t) + l * 256;
            float acc = bm[h];
            for (int k = 0; k < 256; ++k) acc += bp[k] * Wb[k * 256 + h];
            bc[p * 256 + h] = acc;
        }
        return;
    }
    int blk = blk0 - 774, t = threadIdx.x;
    if (blk < 1536) {
        // WTbig: hi plane only (update main GEMM is 2-term; lo plane is dead)
        int mat = blk >> 8, hh = blk & 255, l = mat >> 1;
        const float* W = ((mat & 1) ? W_pr : W_pt) + l * 512 * 256;
        unsigned short* dh = WTbig + mat * 262144 + hh * 512;
        for (int k = t; k < 512; k += 256)
            dh[k] = f2bf(W[k * 256 + hh]);
    } else {
        int m2 = blk - 1536, mat = m2 >> 8, hh = m2 & 255;
        const float* W;
        if (mat == 6) W = Ws1 + 256 * 256;
        else if (mat == 5) W = Ws1;
        else if (mat & 1) W = W_r2t + ((mat >> 1) + 1) * 512 * 256;
        else W = W_t2r + (mat >> 1) * 512 * 256;
        unsigned short* dh = WT2 + mat * 131072 + hh * 256;
        unsigned short* dl = dh + 65536;
        unsigned short hi, lo;
        split2(W[t * 256 + hh], hi, lo);
        dh[t] = hi; dl[t] = lo;
    }
}

// ---- 2. proj: robot_h/target_h = X @ Wp + bp ; robot WGs also emit rWa0 ----
__global__ __launch_bounds__(256) void k_proj(const float* __restrict__ robot_raw,
                                              const float* __restrict__ traw,
                                              const float* __restrict__ Wp,
                                              const float* __restrict__ bp,
                                              const float* __restrict__ Wa0,
                                              float* __restrict__ robot_h,
                                              float* __restrict__ target_h,
                                              float* __restrict__ rWa) {
    int h = threadIdx.x;
    int r0 = blockIdx.x * 2;
    int robot = (r0 < 512);
    const float* in;
    float* out;
    if (robot) { in = robot_raw + r0 * 128; out = robot_h + r0 * 256; }
    else       { in = traw + (r0 - 512) * 128; out = target_h + (r0 - 512) * 256; }
    float a0 = 0, a1 = 0;
    for (int k = 0; k < 128; ++k) {
        float w = Wp[k * 256 + h];
        a0 += in[k] * w; a1 += in[128 + k] * w;
    }
    float b = bp[h];
    a0 += b; a1 += b;
    out[h] = a0; out[256 + h] = a1;

    __shared__ float yl[2][257];
    if (robot) { yl[0][h] = a0; yl[1][h] = a1; }
    __syncthreads();
    if (robot) {
        float c0 = 0, c1 = 0;
        for (int k = 0; k < 256; ++k) {
            float w = Wa0[k * 256 + h];
            c0 += yl[0][k] * w; c1 += yl[1][k] * w;
        }
        rWa[r0 * 256 + h] = c0; rWa[(r0 + 1) * 256 + h] = c1;
    }
}

// ---- 3. update via MFMA split-bf16, 1024 threads / 16 waves (16 cols each) ----
// main GEMM: 2-term (A bf16x2, B bf16). GEMM2: 3-term.
__global__ __launch_bounds__(1024) void k_update_mfma(
        float* __restrict__ state, const float* __restrict__ agg,
        const unsigned short* __restrict__ WTm,   // [hi 256x512] (lo plane unused)
        const float* __restrict__ bvec, const float* __restrict__ g, const float* __restrict__ be,
        const unsigned short* __restrict__ WT2a,  // [hi 256x256][lo 256x256]
        float* __restrict__ out2a,
        const unsigned short* __restrict__ WT2b, const float* __restrict__ b2b,
        float* __restrict__ out2b) {
    int r0 = blockIdx.x * 16;
    int t = threadIdx.x;
    int w = t >> 6, lane = t & 63;
    int c16 = lane & 15, kg = lane >> 4;
    int col = (w << 4) | c16;

    __shared__ unsigned short Ahi[16 * 512];
    __shared__ unsigned short Alo[16 * 512];
    __shared__ unsigned short Yhi[16 * 256];
    __shared__ unsigned short Ylo[16 * 256];
    __shared__ float red[16][16][2];

    // stage A = [state | agg] rows r0..r0+15 as swizzled hi/lo bf16 (8 elems/thread)
    {
        int row = t & 15, kq = t >> 4;   // kq 0..63 -> 8 K-elems each
        const float* src = (kq < 32) ? (state + (r0 + row) * 256 + kq * 8)
                                     : (agg + (r0 + row) * 256 + (kq - 32) * 8);
        float4 a = *(const float4*)(src);
        float4 b2 = *(const float4*)(src + 4);
        unsigned short h[8], lo[8];
        split2(a.x, h[0], lo[0]); split2(a.y, h[1], lo[1]);
        split2(a.z, h[2], lo[2]); split2(a.w, h[3], lo[3]);
        split2(b2.x, h[4], lo[4]); split2(b2.y, h[5], lo[5]);
        split2(b2.z, h[6], lo[6]); split2(b2.w, h[7], lo[7]);
        int byte = row * 1024 + kq * 16;
        byte ^= (row & 7) << 4;
        ushort4* ph = (ushort4*)((char*)Ahi + byte);
        ph[0] = make_ushort4(h[0], h[1], h[2], h[3]);
        ph[1] = make_ushort4(h[4], h[5], h[6], h[7]);
        ushort4* pl = (ushort4*)((char*)Alo + byte);
        pl[0] = make_ushort4(lo[0], lo[1], lo[2], lo[3]);
        pl[1] = make_ushort4(lo[4], lo[5], lo[6], lo[7]);
    }
    __syncthreads();

    // main GEMM: K=512, 2-term split, 1 col-tile per wave
    f32x4 acc = f32x4{0.f, 0.f, 0.f, 0.f};
    const unsigned short* Bh0 = WTm + col * 512 + kg * 8;
#pragma unroll 4
    for (int ks = 0; ks < 16; ++ks) {
        int ab = c16 * 1024 + ks * 64 + kg * 16;
        ab ^= (c16 & 7) << 4;
        bf16x8 ah = *(const bf16x8*)((const char*)Ahi + ab);
        bf16x8 al = *(const bf16x8*)((const char*)Alo + ab);
        bf16x8 bh = *(const bf16x8*)(Bh0 + ks * 32);
        acc = __builtin_amdgcn_mfma_f32_16x16x32_bf16(ah, bh, acc, 0, 0, 0);
        acc = __builtin_amdgcn_mfma_f32_16x16x32_bf16(al, bh, acc, 0, 0, 0);
    }

    // residual + bias
    float x[4];
    {
        float bv = bvec[col];
#pragma unroll
        for (int r = 0; r < 4; ++r) {
            int row = kg * 4 + r;
            x[r] = acc[r] + state[(r0 + row) * 256 + col] + bv;
        }
    }

    // LN stats: reduce over 16 cols in-wave, then 16 waves via LDS
    float s[4], q[4];
#pragma unroll
    for (int r = 0; r < 4; ++r) {
        s[r] = x[r];
        q[r] = x[r] * x[r];
#pragma unroll
        for (int m = 1; m < 16; m <<= 1) {
            s[r] += __shfl_xor(s[r], m);
            q[r] += __shfl_xor(q[r], m);
        }
    }
    if (c16 == 0) {
#pragma unroll
        for (int r = 0; r < 4; ++r) {
            red[w][kg * 4 + r][0] = s[r];
            red[w][kg * 4 + r][1] = q[r];
        }
    }
    __syncthreads();
    float mr[4], rsr[4];
#pragma unroll
    for (int r = 0; r < 4; ++r) {
        int row = kg * 4 + r;
        float S = 0.f, Q = 0.f;
#pragma unroll
        for (int w2 = 0; w2 < 16; ++w2) { S += red[w2][row][0]; Q += red[w2][row][1]; }
        float m = S * (1.f / 256.f);
        float v = Q * (1.f / 256.f) - m * m;
        mr[r] = m;
        rsr[r] = rsqrtf(v + 1e-5f);
    }

    // y = LN(x): store to state + stage bf16 hi/lo into LDS (swizzled)
    {
        float gg = g[col], bb = be[col];
#pragma unroll
        for (int r = 0; r < 4; ++r) {
            int row = kg * 4 + r;
            float y = (x[r] - mr[r]) * rsr[r] * gg + bb;
            state[(r0 + row) * 256 + col] = y;
            unsigned short yh, yl2;
            split2(y, yh, yl2);
            int byte = (row * 512 + col * 2) ^ ((row & 7) << 4);
            *(unsigned short*)((char*)Yhi + byte) = yh;
            *(unsigned short*)((char*)Ylo + byte) = yl2;
        }
    }
    __syncthreads();

    // fused GEMM(s): y @ W2a (-> out2a), optional y @ W2b + b2b (-> out2b transposed)
    f32x4 acc2 = f32x4{0.f, 0.f, 0.f, 0.f};
    f32x4 acc3 = f32x4{0.f, 0.f, 0.f, 0.f};
    const unsigned short* B2h0 = WT2a + col * 256 + kg * 8;
    const unsigned short* B3h0 = WT2b ? (WT2b + col * 256 + kg * 8) : B2h0;
    int haveB = (WT2b != nullptr);
#pragma unroll 4
    for (int ks = 0; ks < 8; ++ks) {
        int ab = c16 * 512 + ks * 64 + kg * 16;
        ab ^= (c16 & 7) << 4;
        bf16x8 ah = *(const bf16x8*)((const char*)Yhi + ab);
        bf16x8 al = *(const bf16x8*)((const char*)Ylo + ab);
        const unsigned short* p = B2h0 + ks * 32;
        bf16x8 bh = *(const bf16x8*)p;
        bf16x8 bl = *(const bf16x8*)(p + 65536);
        acc2 = __builtin_amdgcn_mfma_f32_16x16x32_bf16(ah, bh, acc2, 0, 0, 0);
        acc2 = __builtin_amdgcn_mfma_f32_16x16x32_bf16(al, bh, acc2, 0, 0, 0);
        acc2 = __builtin_amdgcn_mfma_f32_16x16x32_bf16(ah, bl, acc2, 0, 0, 0);
        if (haveB) {
            const unsigned short* p3 = B3h0 + ks * 32;
            bf16x8 bh3 = *(const bf16x8*)p3;
            bf16x8 bl3 = *(const bf16x8*)(p3 + 65536);
            acc3 = __builtin_amdgcn_mfma_f32_16x16x32_bf16(ah, bh3, acc3, 0, 0, 0);
            acc3 = __builtin_amdgcn_mfma_f32_16x16x32_bf16(al, bh3, acc3, 0, 0, 0);
            acc3 = __builtin_amdgcn_mfma_f32_16x16x32_bf16(ah, bl3, acc3, 0, 0, 0);
        }
    }
#pragma unroll
    for (int r = 0; r < 4; ++r) {
        int row = kg * 4 + r;
        out2a[(r0 + row) * 256 + col] = acc2[r];
    }
    if (haveB) {
        float bb2 = b2b[col];
#pragma unroll
        for (int r = 0; r < 4; ++r) {
            int grow = r0 + kg * 4 + r;
            int b0 = grow >> 6, j = grow & 63;
            out2b[(b0 * 256 + col) * 64 + j] = acc3[r] + bb2;
        }
    }
}

// ---- 4. bigpass: hoisted loads; prefetch issued mid-kernel, consumed at end ----
__global__ __launch_bounds__(256) void k_bigpass(const unsigned short* __restrict__ edge_bf,
                                                 const unsigned short* __restrict__ WcT,
                                                 const float* __restrict__ bc,
                                                 const float* __restrict__ rowbias,
                                                 float* __restrict__ agg,
                                                 int mode,
                                                 const unsigned short* __restrict__ prefA,
                                                 const unsigned short* __restrict__ prefB,
                                                 int nb) {            // nb = uint4 count of B slice
    int wg = blockIdx.x;                 // 512 = b*64 + jj
    int b = wg >> 6, jj = wg & 63;
    int w = threadIdx.x >> 6, lane = threadIdx.x & 63;
    int row16 = lane & 15, kgrp = lane >> 4;

    int rstride = (mode == 0) ? 8192 : 128;
    const unsigned short* Ap = edge_bf + b * 524288 + ((mode == 0) ? jj * 128 : jj * 8192)
                             + row16 * rstride + 8 * kgrp;
    const unsigned short* Bp = WcT + (64 * w + row16) * 128 + 8 * kgrp;

    // hoist ALL fragment loads: one latency window
    bf16x8 av[4][4], bv[4][4];
#pragma unroll
    for (int kk = 0; kk < 4; ++kk) {
#pragma unroll
        for (int mi = 0; mi < 4; ++mi)
            av[mi][kk] = *(const bf16x8*)(Ap + mi * 16 * rstride + kk * 32);
#pragma unroll
        for (int ni = 0; ni < 4; ++ni)
            bv[ni][kk] = *(const bf16x8*)(Bp + ni * 2048 + kk * 32);
    }
    __builtin_amdgcn_sched_barrier(0);

    f32x4 acc[4][4];
#pragma unroll
    for (int mi = 0; mi < 4; ++mi)
#pragma unroll
        for (int ni = 0; ni < 4; ++ni) acc[mi][ni] = f32x4{0.f, 0.f, 0.f, 0.f};
#pragma unroll
    for (int kk = 0; kk < 4; ++kk)
#pragma unroll
        for (int mi = 0; mi < 4; ++mi)
#pragma unroll
            for (int ni = 0; ni < 4; ++ni)
                acc[mi][ni] = __builtin_amdgcn_mfma_f32_16x16x32_bf16(av[mi][kk], bv[ni][kk], acc[mi][ni], 0, 0, 0);

    // issue prefetch loads now (next update's weight panels, 1/64 slice);
    // their latency overlaps the epilogue, consumed at kernel end.
    // A slice = 256 uint4 (hi plane only, 256KB total).
    int s = (blockIdx.x >> 3) & 63;
    const uint4* pa = (const uint4*)prefA + (long)s * 256;
    const uint4* pb = (const uint4*)prefB + (long)s * nb;
    uint4 pf0 = pa[threadIdx.x];
    uint4 pf2 = pb[threadIdx.x];
    uint4 pf3, pf4;
    int big = (nb > 256);
    if (big) { pf3 = pb[threadIdx.x + 256]; pf4 = pb[threadIdx.x + 512]; }
    __builtin_amdgcn_sched_barrier(0);

    const float* rb = rowbias + (b * 64) * 256;
    float colsum[4] = {0.f, 0.f, 0.f, 0.f};
#pragma unroll
    for (int ni = 0; ni < 4; ++ni) {
        int col = 64 * w + 16 * ni + row16;
        float bch = bc[col];
#pragma unroll
        for (int mi = 0; mi < 4; ++mi) {
            int rbase = 16 * mi + 4 * kgrp;
#pragma unroll
            for (int r = 0; r < 4; ++r) {
                float v = acc[mi][ni][r] + rb[(rbase + r) * 256 + col] + bch;
                colsum[ni] += fmaxf(v, 0.f);
            }
        }
    }
#pragma unroll
    for (int ni = 0; ni < 4; ++ni) {
        colsum[ni] += __shfl_xor(colsum[ni], 16);
        colsum[ni] += __shfl_xor(colsum[ni], 32);
    }
    if (kgrp == 0) {
        float* o = agg + (b * 64 + jj) * 256 + 64 * w + row16;
#pragma unroll
        for (int ni = 0; ni < 4; ++ni) o[16 * ni] = colsum[ni] * (1.f / 64.f);
    }

    unsigned accp = pf0.x ^ pf0.w ^ pf2.z;
    if (big) accp ^= pf3.x ^ pf4.w;
    asm volatile("" :: "v"(accp));
}

// ---- 5. scores ----
__global__ __launch_bounds__(256) void k_scores(const float* __restrict__ rS,
                                                const float* __restrict__ tST,
                                                const float* __restrict__ Ws2,
                                                const float* __restrict__ bs2,
                                                float* __restrict__ scores) {
    int t = blockIdx.x * 256 + threadIdx.x;          // 32768
    int j = t & 63, i = (t >> 6) & 63, b = t >> 12;
    const float* rs = rS + (b * 64 + i) * 256;
    const float* ts = tST + b * 256 * 64 + j;
    float acc = bs2[0];
    for (int h = 0; h < 256; ++h)
        acc += fmaxf(rs[h] + ts[h * 64], 0.f) * Ws2[h];
    scores[t] = acc;
}

// ---- 6. sinkhorn: 1024 threads, v[4]/thread ----
__global__ __launch_bounds__(1024) void k_sinkhorn(const float* __restrict__ scores,
                                                   float* __restrict__ probs) {
    int b = blockIdx.x;
    int t = threadIdx.x;
    int j = t & 63, rg = t >> 6;         // 16 row-groups x 4 rows
    float v[4];
    const float* src = scores + b * 4096 + rg * 256 + j;
#pragma unroll
    for (int k = 0; k < 4; ++k) v[k] = src[k * 64];

    __shared__ float lm_s[2][16][64];
    __shared__ float ps_s[2][16][64];

    for (int it = 0; it < 10; ++it) {
#pragma unroll
        for (int k = 0; k < 4; ++k) {
            float m = v[k];
#pragma unroll
            for (int s = 1; s < 64; s <<= 1) m = fmaxf(m, __shfl_xor(m, s));
            float e = __expf(v[k] - m), ss = e;
#pragma unroll
            for (int s = 1; s < 64; s <<= 1) ss += __shfl_xor(ss, s);
            v[k] -= m + __logf(ss);
        }
        int p = it & 1;
        float lm = fmaxf(fmaxf(v[0], v[1]), fmaxf(v[2], v[3]));
        float ps = __expf(v[0] - lm) + __expf(v[1] - lm) + __expf(v[2] - lm) + __expf(v[3] - lm);
        lm_s[p][rg][j] = lm; ps_s[p][rg][j] = ps;
        __syncthreads();
        float M = lm_s[p][0][j];
#pragma unroll
        for (int g2 = 1; g2 < 16; ++g2) M = fmaxf(M, lm_s[p][g2][j]);
        float S = 0.f;
#pragma unroll
        for (int g2 = 0; g2 < 16; ++g2) S += ps_s[p][g2][j] * __expf(lm_s[p][g2][j] - M);
        float lse = M + __logf(S);
#pragma unroll
        for (int k = 0; k < 4; ++k) v[k] -= lse;
    }
    float* dst = probs + b * 4096 + rg * 256 + j;
#pragma unroll
    for (int k = 0; k < 4; ++k) dst[k * 64] = __expf(v[k]);
}

extern "C" void kernel_launch(void* const* d_in, const int* in_sizes, int n_in,
                              void* d_out, int out_size, void* d_ws, size_t ws_size,
                              hipStream_t stream) {
    const float* robot_raw = (const float*)d_in[0];
    const float* edge_raw  = (const float*)d_in[1];
    const float* Wp    = (const float*)d_in[2];
    const float* bp    = (const float*)d_in[3];
    const float* W_r2t = (const float*)d_in[4];
    const float* b_r2t = (const float*)d_in[5];
    const float* W_pt  = (const float*)d_in[6];
    const float* b_pt  = (const float*)d_in[7];
    const float* g_t   = (const float*)d_in[8];
    const float* be_t  = (const float*)d_in[9];
    const float* W_t2r = (const float*)d_in[10];
    const float* b_t2r = (const float*)d_in[11];
    const float* W_pr  = (const float*)d_in[12];
    const float* b_pr  = (const float*)d_in[13];
    const float* g_r   = (const float*)d_in[14];
    const float* be_r  = (const float*)d_in[15];
    const float* Ws1   = (const float*)d_in[16];
    const float* bs1   = (const float*)d_in[17];
    const float* Ws2   = (const float*)d_in[18];
    const float* bs2   = (const float*)d_in[19];

    char* ws = (char*)d_ws;
    unsigned short* edge_bf = (unsigned short*)(ws);            // 8,388,608
    float* traw     = (float*)(ws + 8388608);                   //   262,144
    float* robot_h  = (float*)(ws + 8650752);                   //   524,288
    float* target_h = (float*)(ws + 9175040);                   //   524,288
    unsigned short* WcT = (unsigned short*)(ws + 9699328);      //   393,216
    float* bc       = (float*)(ws + 10092544);                  //     6,144
    float* rWa      = (float*)(ws + 10098688);                  //   524,288
    float* tWa      = (float*)(ws + 10622976);                  //   524,288
    float* agg      = (float*)(ws + 11147264);                  //   524,288
    float* rS       = (float*)(ws + 11671552);                  //   524,288
    float* tST      = (float*)(ws + 12195840);                  //   524,288
    unsigned short* WTbig = (unsigned short*)(ws + 12720128);   // 3,145,728 (hi planes used)
    unsigned short* WT2   = (unsigned short*)(ws + 15865856);   // 1,835,008

    float* out    = (float*)d_out;
    float* probs  = out;            // output 0
    float* scores = out + 32768;    // output 1

    hipLaunchKernelGGL(k_prep_w, dim3(4614), dim3(256), 0, stream,
                       edge_raw, edge_bf, traw,
                       Wp, bp, W_r2t, b_r2t, W_t2r, b_t2r, W_pt, W_pr, Ws1, WcT, bc, WTbig, WT2);
    hipLaunchKernelGGL(k_proj, dim3(512), dim3(256), 0, stream,
                       robot_raw, traw, Wp, bp, W_r2t, robot_h, target_h, rWa);

    for (int l = 0; l < 3; ++l) {
        // r2t bigpass + prefetch of the target-update weights (hi plane + WT2)
        {
            const unsigned short* pA = WTbig + (2 * l) * 262144;
            const unsigned short* pB = WT2 + (2 * l) * 131072;
            int nb = (l == 2) ? 768 : 256;                     // l==2 covers mats 4..6
            hipLaunchKernelGGL(k_bigpass, dim3(512), dim3(256), 0, stream,
                               edge_bf, WcT + (2 * l) * 32768, bc + (2 * l) * 256, rWa, agg, 0,
                               pA, pB, nb);
        }
        const unsigned short* W2b = (l == 2) ? (WT2 + 6 * 131072) : nullptr;
        const float* b2b = (l == 2) ? bs1 : nullptr;
        float* o2b = (l == 2) ? tST : nullptr;
        hipLaunchKernelGGL(k_update_mfma, dim3(32), dim3(1024), 0, stream,
                           target_h, agg, WTbig + (2 * l) * 262144,
                           b_pt + l * 256, g_t + l * 256, be_t + l * 256,
                           WT2 + (2 * l) * 131072, tWa, W2b, b2b, o2b);
        // t2r bigpass + prefetch of the robot-update weights
        {
            const unsigned short* pA = WTbig + (2 * l + 1) * 262144;
            int m2 = (l < 2) ? (2 * l + 1) : 5;
            const unsigned short* pB = WT2 + m2 * 131072;
            hipLaunchKernelGGL(k_bigpass, dim3(512), dim3(256), 0, stream,
                               edge_bf, WcT + (2 * l + 1) * 32768, bc + (2 * l + 1) * 256, tWa, agg, 1,
                               pA, pB, 256);
        }
        const unsigned short* W2a = (l < 2) ? (WT2 + (2 * l + 1) * 131072) : (WT2 + 5 * 131072);
        float* o2a = (l < 2) ? rWa : rS;
        hipLaunchKernelGGL(k_update_mfma, dim3(32), dim3(1024), 0, stream,
                           robot_h, agg, WTbig + (2 * l + 1) * 262144,
                           b_pr + l * 256, g_r + l * 256, be_r + l * 256,
                           W2a, o2a, (const unsigned short*)nullptr, (const float*)nullptr, (float*)nullptr);
    }

    hipLaunchKernelGGL(k_scores, dim3(128), dim3(256), 0, stream, rS, tST, Ws2, bs2, scores);
    hipLaunchKernelGGL(k_sinkhorn, dim3(8), dim3(1024), 0, stream, scores, probs);
}

// Round 13
// 257.526 us; speedup vs baseline: 2.8527x; 1.0944x over previous
//
#include <hip/hip_runtime.h>

// NavAssignNet on MI355X — round 13: R12 + GEMM2 also 2-term (B plain bf16).
// R12 proved updates are weight-stream-bound (-40us from halving WTm) and
// that B-lo planes don't move absmax (edge-path bf16 dominates). WT2 lo
// planes now dead: not written, not prefetched, not streamed.

typedef short bf16x8 __attribute__((ext_vector_type(8)));
typedef float f32x4 __attribute__((ext_vector_type(4)));

#define DEV static __device__ __forceinline__

DEV unsigned short f2bf(float x) {
    unsigned u = __float_as_uint(x);
    return (unsigned short)((u + 0x7fffu + ((u >> 16) & 1u)) >> 16);
}
DEV void split2(float v, unsigned short& hi, unsigned short& lo) {
    unsigned short h = f2bf(v);
    float fh = __uint_as_float(((unsigned)h) << 16);
    hi = h;
    lo = f2bf(v - fh);
}

// ---- 1. prep+weights merged ----
__global__ __launch_bounds__(256) void k_prep_w(const float* __restrict__ edge,
                                                unsigned short* __restrict__ edge_bf,
                                                float* __restrict__ traw,
                                                const float* __restrict__ Wp,
                                                const float* __restrict__ bp,
                                                const float* __restrict__ W_r2t,
                                                const float* __restrict__ b_r2t,
                                                const float* __restrict__ W_t2r,
                                                const float* __restrict__ b_t2r,
                                                const float* __restrict__ W_pt,
                                                const float* __restrict__ W_pr,
                                                const float* __restrict__ Ws1,
                                                unsigned short* __restrict__ WcT,
                                                float* __restrict__ bc,
                                                unsigned short* __restrict__ WTbig,
                                                unsigned short* __restrict__ WT2) {
    if (blockIdx.x < 512) {
        int wg = blockIdx.x;             // b*64 + j
        int b = wg >> 6, j = wg & 63;
        int t = threadIdx.x;
        int d = t & 127, ih = t >> 7;
        float s = 0.f;
        long base = ((long)(b * 64 + ih * 32) * 64 + j) * 128 + d;
#pragma unroll 8
        for (int ii = 0; ii < 32; ++ii) {
            long idx = base + (long)ii * 8192;
            float v = edge[idx];
            s += v;
            edge_bf[idx] = f2bf(v);
        }
        __shared__ float part[128];
        if (ih == 1) part[d] = s;
        __syncthreads();
        if (ih == 0) traw[(b * 64 + j) * 128 + d] = (s + part[d]) * (1.f / 64.f);
        return;
    }
    int blk0 = blockIdx.x - 512;
    int h = threadIdx.x;
    if (blk0 < 774) {
        int blk = blk0;
        if (blk < 768) {
            int p = blk >> 7, d = blk & 127, l = p >> 1;
            const float* Wb = ((p & 1) ? W_t2r : W_r2t) + l * 512 * 256 + 256 * 256;
            float acc = 0.f;
            for (int k = 0; k < 256; ++k) acc += Wp[d * 256 + k] * Wb[k * 256 + h];
            WcT[p * 32768 + h * 128 + d] = f2bf(acc);
        } else {
            int p = blk - 768, l = p >> 1;
            const float* Wb = ((p & 1) ? W_t2r : W_r2t) + l * 512 * 256 + 256 * 256;
            const float* bm = ((p & 1) ? b_t2r : b_r2t) + l * 256;
            float acc = bm[h];
            for (int k = 0; k < 256; ++k) acc += bp[k] * Wb[k * 256 + h];
            bc[p * 256 + h] = acc;
        }
        return;
    }
    int blk = blk0 - 774, t = threadIdx.x;
    if (blk < 1536) {
        // WTbig: hi plane only
        int mat = blk >> 8, hh = blk & 255, l = mat >> 1;
        const float* W = ((mat & 1) ? W_pr : W_pt) + l * 512 * 256;
        unsigned short* dh = WTbig + mat * 262144 + hh * 512;
        for (int k = t; k < 512; k += 256)
            dh[k] = f2bf(W[k * 256 + hh]);
    } else {
        // WT2: hi plane only (GEMM2 is 2-term now)
        int m2 = blk - 1536, mat = m2 >> 8, hh = m2 & 255;
        const float* W;
        if (mat == 6) W = Ws1 + 256 * 256;
        else if (mat == 5) W = Ws1;
        else if (mat & 1) W = W_r2t + ((mat >> 1) + 1) * 512 * 256;
        else W = W_t2r + (mat >> 1) * 512 * 256;
        WT2[mat * 65536 + hh * 256 + t] = f2bf(W[t * 256 + hh]);
    }
}

// ---- 2. proj: robot_h/target_h = X @ Wp + bp ; robot WGs also emit rWa0 ----
__global__ __launch_bounds__(256) void k_proj(const float* __restrict__ robot_raw,
                                              const float* __restrict__ traw,
                                              const float* __restrict__ Wp,
                                              const float* __restrict__ bp,
                                              const float* __restrict__ Wa0,
                                              float* __restrict__ robot_h,
                                              float* __restrict__ target_h,
                                              float* __restrict__ rWa) {
    int h = threadIdx.x;
    int r0 = blockIdx.x * 2;
    int robot = (r0 < 512);
    const float* in;
    float* out;
    if (robot) { in = robot_raw + r0 * 128; out = robot_h + r0 * 256; }
    else       { in = traw + (r0 - 512) * 128; out = target_h + (r0 - 512) * 256; }
    float a0 = 0, a1 = 0;
    for (int k = 0; k < 128; ++k) {
        float w = Wp[k * 256 + h];
        a0 += in[k] * w; a1 += in[128 + k] * w;
    }
    float b = bp[h];
    a0 += b; a1 += b;
    out[h] = a0; out[256 + h] = a1;

    __shared__ float yl[2][257];
    if (robot) { yl[0][h] = a0; yl[1][h] = a1; }
    __syncthreads();
    if (robot) {
        float c0 = 0, c1 = 0;
        for (int k = 0; k < 256; ++k) {
            float w = Wa0[k * 256 + h];
            c0 += yl[0][k] * w; c1 += yl[1][k] * w;
        }
        rWa[r0 * 256 + h] = c0; rWa[(r0 + 1) * 256 + h] = c1;
    }
}

// ---- 3. update via MFMA split-bf16, 1024 threads / 16 waves (16 cols each) ----
// Both GEMMs 2-term: A in bf16 hi/lo, B plain bf16.
__global__ __launch_bounds__(1024) void k_update_mfma(
        float* __restrict__ state, const float* __restrict__ agg,
        const unsigned short* __restrict__ WTm,   // [hi 256x512]
        const float* __restrict__ bvec, const float* __restrict__ g, const float* __restrict__ be,
        const unsigned short* __restrict__ WT2a,  // [hi 256x256]
        float* __restrict__ out2a,
        const unsigned short* __restrict__ WT2b, const float* __restrict__ b2b,
        float* __restrict__ out2b) {
    int r0 = blockIdx.x * 16;
    int t = threadIdx.x;
    int w = t >> 6, lane = t & 63;
    int c16 = lane & 15, kg = lane >> 4;
    int col = (w << 4) | c16;

    __shared__ unsigned short Ahi[16 * 512];
    __shared__ unsigned short Alo[16 * 512];
    __shared__ unsigned short Yhi[16 * 256];
    __shared__ unsigned short Ylo[16 * 256];
    __shared__ float red[16][16][2];

    // stage A = [state | agg] rows r0..r0+15 as swizzled hi/lo bf16 (8 elems/thread)
    {
        int row = t & 15, kq = t >> 4;   // kq 0..63 -> 8 K-elems each
        const float* src = (kq < 32) ? (state + (r0 + row) * 256 + kq * 8)
                                     : (agg + (r0 + row) * 256 + (kq - 32) * 8);
        float4 a = *(const float4*)(src);
        float4 b2 = *(const float4*)(src + 4);
        unsigned short h[8], lo[8];
        split2(a.x, h[0], lo[0]); split2(a.y, h[1], lo[1]);
        split2(a.z, h[2], lo[2]); split2(a.w, h[3], lo[3]);
        split2(b2.x, h[4], lo[4]); split2(b2.y, h[5], lo[5]);
        split2(b2.z, h[6], lo[6]); split2(b2.w, h[7], lo[7]);
        int byte = row * 1024 + kq * 16;
        byte ^= (row & 7) << 4;
        ushort4* ph = (ushort4*)((char*)Ahi + byte);
        ph[0] = make_ushort4(h[0], h[1], h[2], h[3]);
        ph[1] = make_ushort4(h[4], h[5], h[6], h[7]);
        ushort4* pl = (ushort4*)((char*)Alo + byte);
        pl[0] = make_ushort4(lo[0], lo[1], lo[2], lo[3]);
        pl[1] = make_ushort4(lo[4], lo[5], lo[6], lo[7]);
    }
    __syncthreads();

    // main GEMM: K=512, 2-term split, 1 col-tile per wave
    f32x4 acc = f32x4{0.f, 0.f, 0.f, 0.f};
    const unsigned short* Bh0 = WTm + col * 512 + kg * 8;
#pragma unroll 4
    for (int ks = 0; ks < 16; ++ks) {
        int ab = c16 * 1024 + ks * 64 + kg * 16;
        ab ^= (c16 & 7) << 4;
        bf16x8 ah = *(const bf16x8*)((const char*)Ahi + ab);
        bf16x8 al = *(const bf16x8*)((const char*)Alo + ab);
        bf16x8 bh = *(const bf16x8*)(Bh0 + ks * 32);
        acc = __builtin_amdgcn_mfma_f32_16x16x32_bf16(ah, bh, acc, 0, 0, 0);
        acc = __builtin_amdgcn_mfma_f32_16x16x32_bf16(al, bh, acc, 0, 0, 0);
    }

    // residual + bias
    float x[4];
    {
        float bv = bvec[col];
#pragma unroll
        for (int r = 0; r < 4; ++r) {
            int row = kg * 4 + r;
            x[r] = acc[r] + state[(r0 + row) * 256 + col] + bv;
        }
    }

    // LN stats: reduce over 16 cols in-wave, then 16 waves via LDS
    float s[4], q[4];
#pragma unroll
    for (int r = 0; r < 4; ++r) {
        s[r] = x[r];
        q[r] = x[r] * x[r];
#pragma unroll
        for (int m = 1; m < 16; m <<= 1) {
            s[r] += __shfl_xor(s[r], m);
            q[r] += __shfl_xor(q[r], m);
        }
    }
    if (c16 == 0) {
#pragma unroll
        for (int r = 0; r < 4; ++r) {
            red[w][kg * 4 + r][0] = s[r];
            red[w][kg * 4 + r][1] = q[r];
        }
    }
    __syncthreads();
    float mr[4], rsr[4];
#pragma unroll
    for (int r = 0; r < 4; ++r) {
        int row = kg * 4 + r;
        float S = 0.f, Q = 0.f;
#pragma unroll
        for (int w2 = 0; w2 < 16; ++w2) { S += red[w2][row][0]; Q += red[w2][row][1]; }
        float m = S * (1.f / 256.f);
        float v = Q * (1.f / 256.f) - m * m;
        mr[r] = m;
        rsr[r] = rsqrtf(v + 1e-5f);
    }

    // y = LN(x): store to state + stage bf16 hi/lo into LDS (swizzled)
    {
        float gg = g[col], bb = be[col];
#pragma unroll
        for (int r = 0; r < 4; ++r) {
            int row = kg * 4 + r;
            float y = (x[r] - mr[r]) * rsr[r] * gg + bb;
            state[(r0 + row) * 256 + col] = y;
            unsigned short yh, yl2;
            split2(y, yh, yl2);
            int byte = (row * 512 + col * 2) ^ ((row & 7) << 4);
            *(unsigned short*)((char*)Yhi + byte) = yh;
            *(unsigned short*)((char*)Ylo + byte) = yl2;
        }
    }
    __syncthreads();

    // fused GEMM(s), 2-term: y @ W2a (-> out2a), optional y @ W2b + b2b (-> out2b T)
    f32x4 acc2 = f32x4{0.f, 0.f, 0.f, 0.f};
    f32x4 acc3 = f32x4{0.f, 0.f, 0.f, 0.f};
    const unsigned short* B2h0 = WT2a + col * 256 + kg * 8;
    const unsigned short* B3h0 = WT2b ? (WT2b + col * 256 + kg * 8) : B2h0;
    int haveB = (WT2b != nullptr);
#pragma unroll 4
    for (int ks = 0; ks < 8; ++ks) {
        int ab = c16 * 512 + ks * 64 + kg * 16;
        ab ^= (c16 & 7) << 4;
        bf16x8 ah = *(const bf16x8*)((const char*)Yhi + ab);
        bf16x8 al = *(const bf16x8*)((const char*)Ylo + ab);
        bf16x8 bh = *(const bf16x8*)(B2h0 + ks * 32);
        acc2 = __builtin_amdgcn_mfma_f32_16x16x32_bf16(ah, bh, acc2, 0, 0, 0);
        acc2 = __builtin_amdgcn_mfma_f32_16x16x32_bf16(al, bh, acc2, 0, 0, 0);
        if (haveB) {
            bf16x8 bh3 = *(const bf16x8*)(B3h0 + ks * 32);
            acc3 = __builtin_amdgcn_mfma_f32_16x16x32_bf16(ah, bh3, acc3, 0, 0, 0);
            acc3 = __builtin_amdgcn_mfma_f32_16x16x32_bf16(al, bh3, acc3, 0, 0, 0);
        }
    }
#pragma unroll
    for (int r = 0; r < 4; ++r) {
        int row = kg * 4 + r;
        out2a[(r0 + row) * 256 + col] = acc2[r];
    }
    if (haveB) {
        float bb2 = b2b[col];
#pragma unroll
        for (int r = 0; r < 4; ++r) {
            int grow = r0 + kg * 4 + r;
            int b0 = grow >> 6, j = grow & 63;
            out2b[(b0 * 256 + col) * 64 + j] = acc3[r] + bb2;
        }
    }
}

// ---- 4. bigpass: hoisted loads; prefetch issued mid-kernel, consumed at end ----
__global__ __launch_bounds__(256) void k_bigpass(const unsigned short* __restrict__ edge_bf,
                                                 const unsigned short* __restrict__ WcT,
                                                 const float* __restrict__ bc,
                                                 const float* __restrict__ rowbias,
                                                 float* __restrict__ agg,
                                                 int mode,
                                                 const unsigned short* __restrict__ prefA,
                                                 const unsigned short* __restrict__ prefB,
                                                 int nb) {            // nb = uint4 count of B slice
    int wg = blockIdx.x;                 // 512 = b*64 + jj
    int b = wg >> 6, jj = wg & 63;
    int w = threadIdx.x >> 6, lane = threadIdx.x & 63;
    int row16 = lane & 15, kgrp = lane >> 4;

    int rstride = (mode == 0) ? 8192 : 128;
    const unsigned short* Ap = edge_bf + b * 524288 + ((mode == 0) ? jj * 128 : jj * 8192)
                             + row16 * rstride + 8 * kgrp;
    const unsigned short* Bp = WcT + (64 * w + row16) * 128 + 8 * kgrp;

    // hoist ALL fragment loads: one latency window
    bf16x8 av[4][4], bv[4][4];
#pragma unroll
    for (int kk = 0; kk < 4; ++kk) {
#pragma unroll
        for (int mi = 0; mi < 4; ++mi)
            av[mi][kk] = *(const bf16x8*)(Ap + mi * 16 * rstride + kk * 32);
#pragma unroll
        for (int ni = 0; ni < 4; ++ni)
            bv[ni][kk] = *(const bf16x8*)(Bp + ni * 2048 + kk * 32);
    }
    __builtin_amdgcn_sched_barrier(0);

    f32x4 acc[4][4];
#pragma unroll
    for (int mi = 0; mi < 4; ++mi)
#pragma unroll
        for (int ni = 0; ni < 4; ++ni) acc[mi][ni] = f32x4{0.f, 0.f, 0.f, 0.f};
#pragma unroll
    for (int kk = 0; kk < 4; ++kk)
#pragma unroll
        for (int mi = 0; mi < 4; ++mi)
#pragma unroll
            for (int ni = 0; ni < 4; ++ni)
                acc[mi][ni] = __builtin_amdgcn_mfma_f32_16x16x32_bf16(av[mi][kk], bv[ni][kk], acc[mi][ni], 0, 0, 0);

    // issue prefetch loads now (next update's weight panels, 1/64 slice);
    // A slice = 256 uint4 (hi plane, 256KB); B slice = nb uint4 (hi planes).
    int s = (blockIdx.x >> 3) & 63;
    const uint4* pa = (const uint4*)prefA + (long)s * 256;
    const uint4* pb = (const uint4*)prefB + (long)s * nb;
    uint4 pf0 = pa[threadIdx.x];
    uint4 pf2;
    // nb is 128 or 384; thread 128..255 covers second half via strided read
    int i0 = threadIdx.x & (nb - 1);
    pf2 = pb[i0];
    uint4 pf3;
    int big = (nb > 128);
    if (big) pf3 = pb[128 + (threadIdx.x & 255)];
    __builtin_amdgcn_sched_barrier(0);

    const float* rb = rowbias + (b * 64) * 256;
    float colsum[4] = {0.f, 0.f, 0.f, 0.f};
#pragma unroll
    for (int ni = 0; ni < 4; ++ni) {
        int col = 64 * w + 16 * ni + row16;
        float bch = bc[col];
#pragma unroll
        for (int mi = 0; mi < 4; ++mi) {
            int rbase = 16 * mi + 4 * kgrp;
#pragma unroll
            for (int r = 0; r < 4; ++r) {
                float v = acc[mi][ni][r] + rb[(rbase + r) * 256 + col] + bch;
                colsum[ni] += fmaxf(v, 0.f);
            }
        }
    }
#pragma unroll
    for (int ni = 0; ni < 4; ++ni) {
        colsum[ni] += __shfl_xor(colsum[ni], 16);
        colsum[ni] += __shfl_xor(colsum[ni], 32);
    }
    if (kgrp == 0) {
        float* o = agg + (b * 64 + jj) * 256 + 64 * w + row16;
#pragma unroll
        for (int ni = 0; ni < 4; ++ni) o[16 * ni] = colsum[ni] * (1.f / 64.f);
    }

    unsigned accp = pf0.x ^ pf0.w ^ pf2.z;
    if (big) accp ^= pf3.x;
    asm volatile("" :: "v"(accp));
}

// ---- 5. scores ----
__global__ __launch_bounds__(256) void k_scores(const float* __restrict__ rS,
                                                const float* __restrict__ tST,
                                                const float* __restrict__ Ws2,
                                                const float* __restrict__ bs2,
                                                float* __restrict__ scores) {
    int t = blockIdx.x * 256 + threadIdx.x;          // 32768
    int j = t & 63, i = (t >> 6) & 63, b = t >> 12;
    const float* rs = rS + (b * 64 + i) * 256;
    const float* ts = tST + b * 256 * 64 + j;
    float acc = bs2[0];
    for (int h = 0; h < 256; ++h)
        acc += fmaxf(rs[h] + ts[h * 64], 0.f) * Ws2[h];
    scores[t] = acc;
}

// ---- 6. sinkhorn: 1024 threads, v[4]/thread ----
__global__ __launch_bounds__(1024) void k_sinkhorn(const float* __restrict__ scores,
                                                   float* __restrict__ probs) {
    int b = blockIdx.x;
    int t = threadIdx.x;
    int j = t & 63, rg = t >> 6;         // 16 row-groups x 4 rows
    float v[4];
    const float* src = scores + b * 4096 + rg * 256 + j;
#pragma unroll
    for (int k = 0; k < 4; ++k) v[k] = src[k * 64];

    __shared__ float lm_s[2][16][64];
    __shared__ float ps_s[2][16][64];

    for (int it = 0; it < 10; ++it) {
#pragma unroll
        for (int k = 0; k < 4; ++k) {
            float m = v[k];
#pragma unroll
            for (int s = 1; s < 64; s <<= 1) m = fmaxf(m, __shfl_xor(m, s));
            float e = __expf(v[k] - m), ss = e;
#pragma unroll
            for (int s = 1; s < 64; s <<= 1) ss += __shfl_xor(ss, s);
            v[k] -= m + __logf(ss);
        }
        int p = it & 1;
        float lm = fmaxf(fmaxf(v[0], v[1]), fmaxf(v[2], v[3]));
        float ps = __expf(v[0] - lm) + __expf(v[1] - lm) + __expf(v[2] - lm) + __expf(v[3] - lm);
        lm_s[p][rg][j] = lm; ps_s[p][rg][j] = ps;
        __syncthreads();
        float M = lm_s[p][0][j];
#pragma unroll
        for (int g2 = 1; g2 < 16; ++g2) M = fmaxf(M, lm_s[p][g2][j]);
        float S = 0.f;
#pragma unroll
        for (int g2 = 0; g2 < 16; ++g2) S += ps_s[p][g2][j] * __expf(lm_s[p][g2][j] - M);
        float lse = M + __logf(S);
#pragma unroll
        for (int k = 0; k < 4; ++k) v[k] -= lse;
    }
    float* dst = probs + b * 4096 + rg * 256 + j;
#pragma unroll
    for (int k = 0; k < 4; ++k) dst[k * 64] = __expf(v[k]);
}

extern "C" void kernel_launch(void* const* d_in, const int* in_sizes, int n_in,
                              void* d_out, int out_size, void* d_ws, size_t ws_size,
                              hipStream_t stream) {
    const float* robot_raw = (const float*)d_in[0];
    const float* edge_raw  = (const float*)d_in[1];
    const float* Wp    = (const float*)d_in[2];
    const float* bp    = (const float*)d_in[3];
    const float* W_r2t = (const float*)d_in[4];
    const float* b_r2t = (const float*)d_in[5];
    const float* W_pt  = (const float*)d_in[6];
    const float* b_pt  = (const float*)d_in[7];
    const float* g_t   = (const float*)d_in[8];
    const float* be_t  = (const float*)d_in[9];
    const float* W_t2r = (const float*)d_in[10];
    const float* b_t2r = (const float*)d_in[11];
    const float* W_pr  = (const float*)d_in[12];
    const float* b_pr  = (const float*)d_in[13];
    const float* g_r   = (const float*)d_in[14];
    const float* be_r  = (const float*)d_in[15];
    const float* Ws1   = (const float*)d_in[16];
    const float* bs1   = (const float*)d_in[17];
    const float* Ws2   = (const float*)d_in[18];
    const float* bs2   = (const float*)d_in[19];

    char* ws = (char*)d_ws;
    unsigned short* edge_bf = (unsigned short*)(ws);            // 8,388,608
    float* traw     = (float*)(ws + 8388608);                   //   262,144
    float* robot_h  = (float*)(ws + 8650752);                   //   524,288
    float* target_h = (float*)(ws + 9175040);                   //   524,288
    unsigned short* WcT = (unsigned short*)(ws + 9699328);      //   393,216
    float* bc       = (float*)(ws + 10092544);                  //     6,144
    float* rWa      = (float*)(ws + 10098688);                  //   524,288
    float* tWa      = (float*)(ws + 10622976);                  //   524,288
    float* agg      = (float*)(ws + 11147264);                  //   524,288
    float* rS       = (float*)(ws + 11671552);                  //   524,288
    float* tST      = (float*)(ws + 12195840);                  //   524,288
    unsigned short* WTbig = (unsigned short*)(ws + 12720128);   // hi planes (mat stride 262144 elems)
    unsigned short* WT2   = (unsigned short*)(ws + 15865856);   // hi planes (mat stride 65536 elems)

    float* out    = (float*)d_out;
    float* probs  = out;            // output 0
    float* scores = out + 32768;    // output 1

    hipLaunchKernelGGL(k_prep_w, dim3(4614), dim3(256), 0, stream,
                       edge_raw, edge_bf, traw,
                       Wp, bp, W_r2t, b_r2t, W_t2r, b_t2r, W_pt, W_pr, Ws1, WcT, bc, WTbig, WT2);
    hipLaunchKernelGGL(k_proj, dim3(512), dim3(256), 0, stream,
                       robot_raw, traw, Wp, bp, W_r2t, robot_h, target_h, rWa);

    for (int l = 0; l < 3; ++l) {
        // r2t bigpass + prefetch of the target-update weights (hi planes)
        {
            const unsigned short* pA = WTbig + (2 * l) * 262144;
            const unsigned short* pB = WT2 + (2 * l) * 65536;
            int nb = (l == 2) ? 384 : 128;                     // l==2 covers mats 4..6
            hipLaunchKernelGGL(k_bigpass, dim3(512), dim3(256), 0, stream,
                               edge_bf, WcT + (2 * l) * 32768, bc + (2 * l) * 256, rWa, agg, 0,
                               pA, pB, nb);
        }
        const unsigned short* W2b = (l == 2) ? (WT2 + 6 * 65536) : nullptr;
        const float* b2b = (l == 2) ? bs1 : nullptr;
        float* o2b = (l == 2) ? tST : nullptr;
        hipLaunchKernelGGL(k_update_mfma, dim3(32), dim3(1024), 0, stream,
                           target_h, agg, WTbig + (2 * l) * 262144,
                           b_pt + l * 256, g_t + l * 256, be_t + l * 256,
                           WT2 + (2 * l) * 65536, tWa, W2b, b2b, o2b);
        // t2r bigpass + prefetch of the robot-update weights
        {
            const unsigned short* pA = WTbig + (2 * l + 1) * 262144;
            int m2 = (l < 2) ? (2 * l + 1) : 5;
            const unsigned short* pB = WT2 + m2 * 65536;
            hipLaunchKernelGGL(k_bigpass, dim3(512), dim3(256), 0, stream,
                               edge_bf, WcT + (2 * l + 1) * 32768, bc + (2 * l + 1) * 256, tWa, agg, 1,
                               pA, pB, 128);
        }
        const unsigned short* W2a = (l < 2) ? (WT2 + (2 * l + 1) * 65536) : (WT2 + 5 * 65536);
        float* o2a = (l < 2) ? rWa : rS;
        hipLaunchKernelGGL(k_update_mfma, dim3(32), dim3(1024), 0, stream,
                           robot_h, agg, WTbig + (2 * l + 1) * 262144,
                           b_pr + l * 256, g_r + l * 256, be_r + l * 256,
                           W2a, o2a, (const unsigned short*)nullptr, (const float*)nullptr, (float*)nullptr);
    }

    hipLaunchKernelGGL(k_scores, dim3(128), dim3(256), 0, stream, rS, tST, Ws2, bs2, scores);
    hipLaunchKernelGGL(k_sinkhorn, dim3(8), dim3(1024), 0, stream, scores, probs);
}

// Round 14
// 251.704 us; speedup vs baseline: 2.9187x; 1.0231x over previous
//
#include <hip/hip_runtime.h>

// NavAssignNet on MI355X — round 14: R13 + (1) k_scores fused into the final
// robot update (rS never leaves the chip: acc2 -> LDS -> scores phase;
// -1 dispatch, -1 gap), (2) first 4 main-GEMM B fragments preloaded before
// A-staging (issue-early: B in flight under the stage+split+barrier phase).

typedef short bf16x8 __attribute__((ext_vector_type(8)));
typedef float f32x4 __attribute__((ext_vector_type(4)));

#define DEV static __device__ __forceinline__

DEV unsigned short f2bf(float x) {
    unsigned u = __float_as_uint(x);
    return (unsigned short)((u + 0x7fffu + ((u >> 16) & 1u)) >> 16);
}
DEV void split2(float v, unsigned short& hi, unsigned short& lo) {
    unsigned short h = f2bf(v);
    float fh = __uint_as_float(((unsigned)h) << 16);
    hi = h;
    lo = f2bf(v - fh);
}

// ---- 1. prep+weights merged ----
__global__ __launch_bounds__(256) void k_prep_w(const float* __restrict__ edge,
                                                unsigned short* __restrict__ edge_bf,
                                                float* __restrict__ traw,
                                                const float* __restrict__ Wp,
                                                const float* __restrict__ bp,
                                                const float* __restrict__ W_r2t,
                                                const float* __restrict__ b_r2t,
                                                const float* __restrict__ W_t2r,
                                                const float* __restrict__ b_t2r,
                                                const float* __restrict__ W_pt,
                                                const float* __restrict__ W_pr,
                                                const float* __restrict__ Ws1,
                                                unsigned short* __restrict__ WcT,
                                                float* __restrict__ bc,
                                                unsigned short* __restrict__ WTbig,
                                                unsigned short* __restrict__ WT2) {
    if (blockIdx.x < 512) {
        int wg = blockIdx.x;             // b*64 + j
        int b = wg >> 6, j = wg & 63;
        int t = threadIdx.x;
        int d = t & 127, ih = t >> 7;
        float s = 0.f;
        long base = ((long)(b * 64 + ih * 32) * 64 + j) * 128 + d;
#pragma unroll 8
        for (int ii = 0; ii < 32; ++ii) {
            long idx = base + (long)ii * 8192;
            float v = edge[idx];
            s += v;
            edge_bf[idx] = f2bf(v);
        }
        __shared__ float part[128];
        if (ih == 1) part[d] = s;
        __syncthreads();
        if (ih == 0) traw[(b * 64 + j) * 128 + d] = (s + part[d]) * (1.f / 64.f);
        return;
    }
    int blk0 = blockIdx.x - 512;
    int h = threadIdx.x;
    if (blk0 < 774) {
        int blk = blk0;
        if (blk < 768) {
            int p = blk >> 7, d = blk & 127, l = p >> 1;
            const float* Wb = ((p & 1) ? W_t2r : W_r2t) + l * 512 * 256 + 256 * 256;
            float acc = 0.f;
            for (int k = 0; k < 256; ++k) acc += Wp[d * 256 + k] * Wb[k * 256 + h];
            WcT[p * 32768 + h * 128 + d] = f2bf(acc);
        } else {
            int p = blk - 768, l = p >> 1;
            const float* Wb = ((p & 1) ? W_t2r : W_r2t) + l * 512 * 256 + 256 * 256;
            const float* bm = ((p & 1) ? b_t2r : b_r2t) + l * 256;
            float acc = bm[h];
            for (int k = 0; k < 256; ++k) acc += bp[k] * Wb[k * 256 + h];
            bc[p * 256 + h] = acc;
        }
        return;
    }
    int blk = blk0 - 774, t = threadIdx.x;
    if (blk < 1536) {
        // WTbig: hi plane only
        int mat = blk >> 8, hh = blk & 255, l = mat >> 1;
        const float* W = ((mat & 1) ? W_pr : W_pt) + l * 512 * 256;
        unsigned short* dh = WTbig + mat * 262144 + hh * 512;
        for (int k = t; k < 512; k += 256)
            dh[k] = f2bf(W[k * 256 + hh]);
    } else {
        // WT2: hi plane only
        int m2 = blk - 1536, mat = m2 >> 8, hh = m2 & 255;
        const float* W;
        if (mat == 6) W = Ws1 + 256 * 256;
        else if (mat == 5) W = Ws1;
        else if (mat & 1) W = W_r2t + ((mat >> 1) + 1) * 512 * 256;
        else W = W_t2r + (mat >> 1) * 512 * 256;
        WT2[mat * 65536 + hh * 256 + t] = f2bf(W[t * 256 + hh]);
    }
}

// ---- 2. proj: robot_h/target_h = X @ Wp + bp ; robot WGs also emit rWa0 ----
__global__ __launch_bounds__(256) void k_proj(const float* __restrict__ robot_raw,
                                              const float* __restrict__ traw,
                                              const float* __restrict__ Wp,
                                              const float* __restrict__ bp,
                                              const float* __restrict__ Wa0,
                                              float* __restrict__ robot_h,
                                              float* __restrict__ target_h,
                                              float* __restrict__ rWa) {
    int h = threadIdx.x;
    int r0 = blockIdx.x * 2;
    int robot = (r0 < 512);
    const float* in;
    float* out;
    if (robot) { in = robot_raw + r0 * 128; out = robot_h + r0 * 256; }
    else       { in = traw + (r0 - 512) * 128; out = target_h + (r0 - 512) * 256; }
    float a0 = 0, a1 = 0;
    for (int k = 0; k < 128; ++k) {
        float w = Wp[k * 256 + h];
        a0 += in[k] * w; a1 += in[128 + k] * w;
    }
    float b = bp[h];
    a0 += b; a1 += b;
    out[h] = a0; out[256 + h] = a1;

    __shared__ float yl[2][257];
    if (robot) { yl[0][h] = a0; yl[1][h] = a1; }
    __syncthreads();
    if (robot) {
        float c0 = 0, c1 = 0;
        for (int k = 0; k < 256; ++k) {
            float w = Wa0[k * 256 + h];
            c0 += yl[0][k] * w; c1 += yl[1][k] * w;
        }
        rWa[r0 * 256 + h] = c0; rWa[(r0 + 1) * 256 + h] = c1;
    }
}

// ---- 3. update via MFMA split-bf16, 1024 threads / 16 waves (16 cols each) ----
// Both GEMMs 2-term. Optional fused scores phase (last robot update).
__global__ __launch_bounds__(1024) void k_update_mfma(
        float* __restrict__ state, const float* __restrict__ agg,
        const unsigned short* __restrict__ WTm,   // [hi 256x512]
        const float* __restrict__ bvec, const float* __restrict__ g, const float* __restrict__ be,
        const unsigned short* __restrict__ WT2a,  // [hi 256x256]
        float* __restrict__ out2a,
        const unsigned short* __restrict__ WT2b, const float* __restrict__ b2b,
        float* __restrict__ out2b,
        const float* __restrict__ tSTg, const float* __restrict__ Ws2v,
        const float* __restrict__ bs2v, float* __restrict__ scoresOut) {
    int r0 = blockIdx.x * 16;
    int t = threadIdx.x;
    int w = t >> 6, lane = t & 63;
    int c16 = lane & 15, kg = lane >> 4;
    int col = (w << 4) | c16;

    __shared__ unsigned short Ahi[16 * 512];
    __shared__ unsigned short Alo[16 * 512];
    __shared__ unsigned short Yhi[16 * 256];
    __shared__ unsigned short Ylo[16 * 256];
    __shared__ float red[16][16][2];

    // preload first 4 main-GEMM B fragments (in flight across the staging phase)
    const unsigned short* Bh0 = WTm + col * 512 + kg * 8;
    bf16x8 bp0 = *(const bf16x8*)(Bh0);
    bf16x8 bp1 = *(const bf16x8*)(Bh0 + 32);
    bf16x8 bp2 = *(const bf16x8*)(Bh0 + 64);
    bf16x8 bp3 = *(const bf16x8*)(Bh0 + 96);

    // stage A = [state | agg] rows r0..r0+15 as swizzled hi/lo bf16 (8 elems/thread)
    {
        int row = t & 15, kq = t >> 4;   // kq 0..63 -> 8 K-elems each
        const float* src = (kq < 32) ? (state + (r0 + row) * 256 + kq * 8)
                                     : (agg + (r0 + row) * 256 + (kq - 32) * 8);
        float4 a = *(const float4*)(src);
        float4 b2 = *(const float4*)(src + 4);
        unsigned short h[8], lo[8];
        split2(a.x, h[0], lo[0]); split2(a.y, h[1], lo[1]);
        split2(a.z, h[2], lo[2]); split2(a.w, h[3], lo[3]);
        split2(b2.x, h[4], lo[4]); split2(b2.y, h[5], lo[5]);
        split2(b2.z, h[6], lo[6]); split2(b2.w, h[7], lo[7]);
        int byte = row * 1024 + kq * 16;
        byte ^= (row & 7) << 4;
        ushort4* ph = (ushort4*)((char*)Ahi + byte);
        ph[0] = make_ushort4(h[0], h[1], h[2], h[3]);
        ph[1] = make_ushort4(h[4], h[5], h[6], h[7]);
        ushort4* pl = (ushort4*)((char*)Alo + byte);
        pl[0] = make_ushort4(lo[0], lo[1], lo[2], lo[3]);
        pl[1] = make_ushort4(lo[4], lo[5], lo[6], lo[7]);
    }
    __syncthreads();

    // main GEMM: K=512, 2-term split, 1 col-tile per wave
    f32x4 acc = f32x4{0.f, 0.f, 0.f, 0.f};
#pragma unroll
    for (int ks = 0; ks < 16; ++ks) {
        int ab = c16 * 1024 + ks * 64 + kg * 16;
        ab ^= (c16 & 7) << 4;
        bf16x8 ah = *(const bf16x8*)((const char*)Ahi + ab);
        bf16x8 al = *(const bf16x8*)((const char*)Alo + ab);
        bf16x8 bh = (ks == 0) ? bp0 : (ks == 1) ? bp1 : (ks == 2) ? bp2 : (ks == 3) ? bp3
                                  : *(const bf16x8*)(Bh0 + ks * 32);
        acc = __builtin_amdgcn_mfma_f32_16x16x32_bf16(ah, bh, acc, 0, 0, 0);
        acc = __builtin_amdgcn_mfma_f32_16x16x32_bf16(al, bh, acc, 0, 0, 0);
    }

    // residual + bias
    float x[4];
    {
        float bv = bvec[col];
#pragma unroll
        for (int r = 0; r < 4; ++r) {
            int row = kg * 4 + r;
            x[r] = acc[r] + state[(r0 + row) * 256 + col] + bv;
        }
    }

    // LN stats: reduce over 16 cols in-wave, then 16 waves via LDS
    float s[4], q[4];
#pragma unroll
    for (int r = 0; r < 4; ++r) {
        s[r] = x[r];
        q[r] = x[r] * x[r];
#pragma unroll
        for (int m = 1; m < 16; m <<= 1) {
            s[r] += __shfl_xor(s[r], m);
            q[r] += __shfl_xor(q[r], m);
        }
    }
    if (c16 == 0) {
#pragma unroll
        for (int r = 0; r < 4; ++r) {
            red[w][kg * 4 + r][0] = s[r];
            red[w][kg * 4 + r][1] = q[r];
        }
    }
    __syncthreads();
    float mr[4], rsr[4];
#pragma unroll
    for (int r = 0; r < 4; ++r) {
        int row = kg * 4 + r;
        float S = 0.f, Q = 0.f;
#pragma unroll
        for (int w2 = 0; w2 < 16; ++w2) { S += red[w2][row][0]; Q += red[w2][row][1]; }
        float m = S * (1.f / 256.f);
        float v = Q * (1.f / 256.f) - m * m;
        mr[r] = m;
        rsr[r] = rsqrtf(v + 1e-5f);
    }

    // y = LN(x): store to state + stage bf16 hi/lo into LDS (swizzled)
    {
        float gg = g[col], bb = be[col];
#pragma unroll
        for (int r = 0; r < 4; ++r) {
            int row = kg * 4 + r;
            float y = (x[r] - mr[r]) * rsr[r] * gg + bb;
            state[(r0 + row) * 256 + col] = y;
            unsigned short yh, yl2;
            split2(y, yh, yl2);
            int byte = (row * 512 + col * 2) ^ ((row & 7) << 4);
            *(unsigned short*)((char*)Yhi + byte) = yh;
            *(unsigned short*)((char*)Ylo + byte) = yl2;
        }
    }
    __syncthreads();

    // fused GEMM(s), 2-term: y @ W2a, optional y @ W2b + b2b (-> out2b T)
    f32x4 acc2 = f32x4{0.f, 0.f, 0.f, 0.f};
    f32x4 acc3 = f32x4{0.f, 0.f, 0.f, 0.f};
    const unsigned short* B2h0 = WT2a + col * 256 + kg * 8;
    const unsigned short* B3h0 = WT2b ? (WT2b + col * 256 + kg * 8) : B2h0;
    int haveB = (WT2b != nullptr);
#pragma unroll 4
    for (int ks = 0; ks < 8; ++ks) {
        int ab = c16 * 512 + ks * 64 + kg * 16;
        ab ^= (c16 & 7) << 4;
        bf16x8 ah = *(const bf16x8*)((const char*)Yhi + ab);
        bf16x8 al = *(const bf16x8*)((const char*)Ylo + ab);
        bf16x8 bh = *(const bf16x8*)(B2h0 + ks * 32);
        acc2 = __builtin_amdgcn_mfma_f32_16x16x32_bf16(ah, bh, acc2, 0, 0, 0);
        acc2 = __builtin_amdgcn_mfma_f32_16x16x32_bf16(al, bh, acc2, 0, 0, 0);
        if (haveB) {
            bf16x8 bh3 = *(const bf16x8*)(B3h0 + ks * 32);
            acc3 = __builtin_amdgcn_mfma_f32_16x16x32_bf16(ah, bh3, acc3, 0, 0, 0);
            acc3 = __builtin_amdgcn_mfma_f32_16x16x32_bf16(al, bh3, acc3, 0, 0, 0);
        }
    }
    if (!scoresOut) {
#pragma unroll
        for (int r = 0; r < 4; ++r) {
            int row = kg * 4 + r;
            out2a[(r0 + row) * 256 + col] = acc2[r];
        }
    }
    if (haveB) {
        float bb2 = b2b[col];
#pragma unroll
        for (int r = 0; r < 4; ++r) {
            int grow = r0 + kg * 4 + r;
            int b0 = grow >> 6, j = grow & 63;
            out2b[(b0 * 256 + col) * 64 + j] = acc3[r] + bb2;
        }
    }

    // fused scores phase (last robot update): rS rows live in LDS (alias Ahi)
    if (scoresOut) {
        float* rSl = (float*)Ahi;        // 16x256 f32 = 16KB, Ahi is dead
#pragma unroll
        for (int r = 0; r < 4; ++r)
            rSl[(kg * 4 + r) * 256 + col] = acc2[r];
        __syncthreads();
        int il = t >> 6, j = t & 63;     // 16 rows x 64 cols = 1024 threads
        int grow = r0 + il, b0 = grow >> 6;
        const float* ts = tSTg + b0 * 16384 + j;
        const float* rsrow = rSl + il * 256;
        float accs = bs2v[0];
        for (int h = 0; h < 256; ++h)
            accs += fmaxf(rsrow[h] + ts[h * 64], 0.f) * Ws2v[h];
        scoresOut[grow * 64 + j] = accs;
    }
}

// ---- 4. bigpass: hoisted loads; prefetch issued mid-kernel, consumed at end ----
__global__ __launch_bounds__(256) void k_bigpass(const unsigned short* __restrict__ edge_bf,
                                                 const unsigned short* __restrict__ WcT,
                                                 const float* __restrict__ bc,
                                                 const float* __restrict__ rowbias,
                                                 float* __restrict__ agg,
                                                 int mode,
                                                 const unsigned short* __restrict__ prefA,
                                                 const unsigned short* __restrict__ prefB,
                                                 int nb) {            // nb = uint4 count of B slice
    int wg = blockIdx.x;                 // 512 = b*64 + jj
    int b = wg >> 6, jj = wg & 63;
    int w = threadIdx.x >> 6, lane = threadIdx.x & 63;
    int row16 = lane & 15, kgrp = lane >> 4;

    int rstride = (mode == 0) ? 8192 : 128;
    const unsigned short* Ap = edge_bf + b * 524288 + ((mode == 0) ? jj * 128 : jj * 8192)
                             + row16 * rstride + 8 * kgrp;
    const unsigned short* Bp = WcT + (64 * w + row16) * 128 + 8 * kgrp;

    // hoist ALL fragment loads: one latency window
    bf16x8 av[4][4], bv[4][4];
#pragma unroll
    for (int kk = 0; kk < 4; ++kk) {
#pragma unroll
        for (int mi = 0; mi < 4; ++mi)
            av[mi][kk] = *(const bf16x8*)(Ap + mi * 16 * rstride + kk * 32);
#pragma unroll
        for (int ni = 0; ni < 4; ++ni)
            bv[ni][kk] = *(const bf16x8*)(Bp + ni * 2048 + kk * 32);
    }
    __builtin_amdgcn_sched_barrier(0);

    f32x4 acc[4][4];
#pragma unroll
    for (int mi = 0; mi < 4; ++mi)
#pragma unroll
        for (int ni = 0; ni < 4; ++ni) acc[mi][ni] = f32x4{0.f, 0.f, 0.f, 0.f};
#pragma unroll
    for (int kk = 0; kk < 4; ++kk)
#pragma unroll
        for (int mi = 0; mi < 4; ++mi)
#pragma unroll
            for (int ni = 0; ni < 4; ++ni)
                acc[mi][ni] = __builtin_amdgcn_mfma_f32_16x16x32_bf16(av[mi][kk], bv[ni][kk], acc[mi][ni], 0, 0, 0);

    // issue prefetch loads now (next update's weight panels, 1/64 slice)
    int s = (blockIdx.x >> 3) & 63;
    const uint4* pa = (const uint4*)prefA + (long)s * 256;
    const uint4* pb = (const uint4*)prefB + (long)s * nb;
    uint4 pf0 = pa[threadIdx.x];
    uint4 pf2;
    int i0 = threadIdx.x & (nb - 1);
    pf2 = pb[i0];
    uint4 pf3;
    int big = (nb > 128);
    if (big) pf3 = pb[128 + (threadIdx.x & 255)];
    __builtin_amdgcn_sched_barrier(0);

    const float* rb = rowbias + (b * 64) * 256;
    float colsum[4] = {0.f, 0.f, 0.f, 0.f};
#pragma unroll
    for (int ni = 0; ni < 4; ++ni) {
        int col = 64 * w + 16 * ni + row16;
        float bch = bc[col];
#pragma unroll
        for (int mi = 0; mi < 4; ++mi) {
            int rbase = 16 * mi + 4 * kgrp;
#pragma unroll
            for (int r = 0; r < 4; ++r) {
                float v = acc[mi][ni][r] + rb[(rbase + r) * 256 + col] + bch;
                colsum[ni] += fmaxf(v, 0.f);
            }
        }
    }
#pragma unroll
    for (int ni = 0; ni < 4; ++ni) {
        colsum[ni] += __shfl_xor(colsum[ni], 16);
        colsum[ni] += __shfl_xor(colsum[ni], 32);
    }
    if (kgrp == 0) {
        float* o = agg + (b * 64 + jj) * 256 + 64 * w + row16;
#pragma unroll
        for (int ni = 0; ni < 4; ++ni) o[16 * ni] = colsum[ni] * (1.f / 64.f);
    }

    unsigned accp = pf0.x ^ pf0.w ^ pf2.z;
    if (big) accp ^= pf3.x;
    asm volatile("" :: "v"(accp));
}

// ---- 5. sinkhorn: 8 WGs x 1024, v[4]/thread ----
__global__ __launch_bounds__(1024) void k_sinkhorn(const float* __restrict__ scores,
                                                   float* __restrict__ probs) {
    int b = blockIdx.x;
    int t = threadIdx.x;
    int j = t & 63, rg = t >> 6;         // 16 row-groups x 4 rows
    float v[4];
    const float* src = scores + b * 4096 + rg * 256 + j;
#pragma unroll
    for (int k = 0; k < 4; ++k) v[k] = src[k * 64];

    __shared__ float lm_s[2][16][64];
    __shared__ float ps_s[2][16][64];

    for (int it = 0; it < 10; ++it) {
#pragma unroll
        for (int k = 0; k < 4; ++k) {
            float m = v[k];
#pragma unroll
            for (int s = 1; s < 64; s <<= 1) m = fmaxf(m, __shfl_xor(m, s));
            float e = __expf(v[k] - m), ss = e;
#pragma unroll
            for (int s = 1; s < 64; s <<= 1) ss += __shfl_xor(ss, s);
            v[k] -= m + __logf(ss);
        }
        int p = it & 1;
        float lm = fmaxf(fmaxf(v[0], v[1]), fmaxf(v[2], v[3]));
        float ps = __expf(v[0] - lm) + __expf(v[1] - lm) + __expf(v[2] - lm) + __expf(v[3] - lm);
        lm_s[p][rg][j] = lm; ps_s[p][rg][j] = ps;
        __syncthreads();
        float M = lm_s[p][0][j];
#pragma unroll
        for (int g2 = 1; g2 < 16; ++g2) M = fmaxf(M, lm_s[p][g2][j]);
        float S = 0.f;
#pragma unroll
        for (int g2 = 0; g2 < 16; ++g2) S += ps_s[p][g2][j] * __expf(lm_s[p][g2][j] - M);
        float lse = M + __logf(S);
#pragma unroll
        for (int k = 0; k < 4; ++k) v[k] -= lse;
    }
    float* dst = probs + b * 4096 + rg * 256 + j;
#pragma unroll
    for (int k = 0; k < 4; ++k) dst[k * 64] = __expf(v[k]);
}

extern "C" void kernel_launch(void* const* d_in, const int* in_sizes, int n_in,
                              void* d_out, int out_size, void* d_ws, size_t ws_size,
                              hipStream_t stream) {
    const float* robot_raw = (const float*)d_in[0];
    const float* edge_raw  = (const float*)d_in[1];
    const float* Wp    = (const float*)d_in[2];
    const float* bp    = (const float*)d_in[3];
    const float* W_r2t = (const float*)d_in[4];
    const float* b_r2t = (const float*)d_in[5];
    const float* W_pt  = (const float*)d_in[6];
    const float* b_pt  = (const float*)d_in[7];
    const float* g_t   = (const float*)d_in[8];
    const float* be_t  = (const float*)d_in[9];
    const float* W_t2r = (const float*)d_in[10];
    const float* b_t2r = (const float*)d_in[11];
    const float* W_pr  = (const float*)d_in[12];
    const float* b_pr  = (const float*)d_in[13];
    const float* g_r   = (const float*)d_in[14];
    const float* be_r  = (const float*)d_in[15];
    const float* Ws1   = (const float*)d_in[16];
    const float* bs1   = (const float*)d_in[17];
    const float* Ws2   = (const float*)d_in[18];
    const float* bs2   = (const float*)d_in[19];

    char* ws = (char*)d_ws;
    unsigned short* edge_bf = (unsigned short*)(ws);            // 8,388,608
    float* traw     = (float*)(ws + 8388608);                   //   262,144
    float* robot_h  = (float*)(ws + 8650752);                   //   524,288
    float* target_h = (float*)(ws + 9175040);                   //   524,288
    unsigned short* WcT = (unsigned short*)(ws + 9699328);      //   393,216
    float* bc       = (float*)(ws + 10092544);                  //     6,144
    float* rWa      = (float*)(ws + 10098688);                  //   524,288
    float* tWa      = (float*)(ws + 10622976);                  //   524,288
    float* agg      = (float*)(ws + 11147264);                  //   524,288
    float* rS       = (float*)(ws + 11671552);                  //   524,288 (unused now)
    float* tST      = (float*)(ws + 12195840);                  //   524,288
    unsigned short* WTbig = (unsigned short*)(ws + 12720128);   // hi planes (mat stride 262144 elems)
    unsigned short* WT2   = (unsigned short*)(ws + 15865856);   // hi planes (mat stride 65536 elems)

    float* out    = (float*)d_out;
    float* probs  = out;            // output 0
    float* scores = out + 32768;    // output 1

    hipLaunchKernelGGL(k_prep_w, dim3(4614), dim3(256), 0, stream,
                       edge_raw, edge_bf, traw,
                       Wp, bp, W_r2t, b_r2t, W_t2r, b_t2r, W_pt, W_pr, Ws1, WcT, bc, WTbig, WT2);
    hipLaunchKernelGGL(k_proj, dim3(512), dim3(256), 0, stream,
                       robot_raw, traw, Wp, bp, W_r2t, robot_h, target_h, rWa);

    for (int l = 0; l < 3; ++l) {
        // r2t bigpass + prefetch of the target-update weights (hi planes)
        {
            const unsigned short* pA = WTbig + (2 * l) * 262144;
            const unsigned short* pB = WT2 + (2 * l) * 65536;
            int nb = (l == 2) ? 384 : 128;                     // l==2 covers mats 4..6
            hipLaunchKernelGGL(k_bigpass, dim3(512), dim3(256), 0, stream,
                               edge_bf, WcT + (2 * l) * 32768, bc + (2 * l) * 256, rWa, agg, 0,
                               pA, pB, nb);
        }
        const unsigned short* W2b = (l == 2) ? (WT2 + 6 * 65536) : nullptr;
        const float* b2b = (l == 2) ? bs1 : nullptr;
        float* o2b = (l == 2) ? tST : nullptr;
        hipLaunchKernelGGL(k_update_mfma, dim3(32), dim3(1024), 0, stream,
                           target_h, agg, WTbig + (2 * l) * 262144,
                           b_pt + l * 256, g_t + l * 256, be_t + l * 256,
                           WT2 + (2 * l) * 65536, tWa, W2b, b2b, o2b,
                           (const float*)nullptr, (const float*)nullptr,
                           (const float*)nullptr, (float*)nullptr);
        // t2r bigpass + prefetch of the robot-update weights
        {
            const unsigned short* pA = WTbig + (2 * l + 1) * 262144;
            int m2 = (l < 2) ? (2 * l + 1) : 5;
            const unsigned short* pB = WT2 + m2 * 65536;
            hipLaunchKernelGGL(k_bigpass, dim3(512), dim3(256), 0, stream,
                               edge_bf, WcT + (2 * l + 1) * 32768, bc + (2 * l + 1) * 256, tWa, agg, 1,
                               pA, pB, 128);
        }
        const unsigned short* W2a = (l < 2) ? (WT2 + (2 * l + 1) * 65536) : (WT2 + 5 * 65536);
        float* o2a = (l < 2) ? rWa : rS;
        // last robot update fuses the scores computation
        const float* fTST = (l == 2) ? tST : nullptr;
        const float* fWs2 = (l == 2) ? Ws2 : nullptr;
        const float* fbs2 = (l == 2) ? bs2 : nullptr;
        float* fScores    = (l == 2) ? scores : nullptr;
        hipLaunchKernelGGL(k_update_mfma, dim3(32), dim3(1024), 0, stream,
                           robot_h, agg, WTbig + (2 * l + 1) * 262144,
                           b_pr + l * 256, g_r + l * 256, be_r + l * 256,
                           W2a, o2a, (const unsigned short*)nullptr, (const float*)nullptr, (float*)nullptr,
                           fTST, fWs2, fbs2, fScores);
    }

    hipLaunchKernelGGL(k_sinkhorn, dim3(8), dim3(1024), 0, stream, scores, probs);
}